// Round 13
// baseline (833.832 us; speedup 1.0000x reference)
//
#include <hip/hip_runtime.h>
#include <hip/hip_bf16.h>

#define Nn 100000
#define Ee 1000000
#define INF_ 100
#define Hh 4
#define Dd 32
#define HD 128
#define Cc 47
#define HC 188
#define HCP 192
#define EPSV 1e-5f
#define SLOPE 0.2f
#define NBLK ((Nn + 255) / 256)

typedef __hip_bfloat16 bf16;
typedef __attribute__((ext_vector_type(8))) short short8;
typedef __attribute__((ext_vector_type(4))) float f32x4;
typedef __attribute__((ext_vector_type(2))) float f32x2;

__device__ __forceinline__ float tof(bf16 v) { return __bfloat162float(v); }
__device__ __forceinline__ float b2f(unsigned short u) {
    return __uint_as_float((unsigned)u << 16);
}
__device__ __forceinline__ float b2flo(unsigned u) {
    return __uint_as_float(u << 16);
}
__device__ __forceinline__ float b2fhi(unsigned u) {
    return __uint_as_float(u & 0xFFFF0000u);
}
__device__ __forceinline__ float ldb(const bf16* p) {
    return b2f(*(const unsigned short*)p);
}
__device__ __forceinline__ unsigned short f2u(float v) {
    bf16 t = __float2bfloat16(v);
    return *(unsigned short*)&t;
}
__device__ __forceinline__ f32x2 pk2(float x, float y) {
    f32x2 r; r.x = x; r.y = y; return r;
}
__device__ __forceinline__ f32x2 pabs2(f32x2 v) {          // v_pk_max_f32 v, -v
    return __builtin_elementwise_max(v, -v);
}
__device__ __forceinline__ f32x2 pfma2(f32x2 a, f32x2 b, f32x2 c) {
    return __builtin_elementwise_fma(a, b, c);             // v_pk_fma_f32
}

// DPP-fused 16-lane reduces (quad_perm swaps + row rotates; row=16 lanes).
template <int C>
__device__ __forceinline__ float dppadd(float v) {
    int m = __builtin_amdgcn_update_dpp(0, __float_as_int(v), C, 0xF, 0xF, false);
    return v + __int_as_float(m);
}
template <int C>
__device__ __forceinline__ float dppmax(float v) {
    int m = __builtin_amdgcn_update_dpp(0, __float_as_int(v), C, 0xF, 0xF, false);
    return fmaxf(v, __int_as_float(m));
}
__device__ __forceinline__ float sum16(float p) {
    p = dppadd<0xB1>(p);   // quad_perm [1,0,3,2]
    p = dppadd<0x4E>(p);   // quad_perm [2,3,0,1]
    p = dppadd<0x124>(p);  // row_ror:4
    p = dppadd<0x128>(p);  // row_ror:8
    return p;
}
__device__ __forceinline__ float max16(float p) {
    p = dppmax<0xB1>(p); p = dppmax<0x4E>(p);
    p = dppmax<0x124>(p); p = dppmax<0x128>(p);
    return p;
}

#define L2E 1.4426950408889634f
#define LN2 0.6931471805599453f

__device__ __forceinline__ float ld_any(const void* p, int i, int isbf) {
    return isbf ? tof(((const bf16*)p)[i]) : ((const float*)p)[i];
}

__device__ __forceinline__ int lbound(const int* __restrict__ dst, int n) {
    int lo = 0, hi = Ee;
    while (lo < hi) {
        int mid = (lo + hi) >> 1;
        if (dst[mid] < n) lo = mid + 1; else hi = mid;
    }
    return lo;
}

// ---------------- MEGA prepare kernel (replaces 5 launches) ----------------
// Each block independently derives the dtype flag (ballot over x[0..255] words,
// L2-hot, deterministic) -> no cross-kernel flag dependency. Jobs partitioned
// by global index: cvt_x | weight pack | small params | src byte-offsets |
// bns zeroing | CSR ptr + BLOCK-LOCAL degree histogram (lower_bounds shared
// through LDS so hist needs no globally-complete ptr).
#define WROWS 1280
#define NSP 15
struct PrepTab { const void* src[8]; int row0[8]; int K[8]; int M[8]; int MP[8]; };
struct CvtTab { const void* src[NSP]; int off[NSP + 1]; };

__global__ __launch_bounds__(256) void prepare(
    const void* __restrict__ x, const int* __restrict__ src,
    const int* __restrict__ dst,
    PrepTab pt, CvtTab ct, int tot,
    bf16* __restrict__ xb, bf16* __restrict__ wtb, bf16* __restrict__ pb,
    unsigned* __restrict__ w384, unsigned* __restrict__ w256,
    int* __restrict__ ptr, int* __restrict__ cnt,
    float* __restrict__ z0, float* __restrict__ z1, int* __restrict__ flag) {
    __shared__ int wc[4];
    __shared__ int lbv[257];
    __shared__ int lh[256];
    const int t = threadIdx.x;
    // ---- per-block dtype detect ----
    unsigned w = ((const unsigned*)x)[t];
    float dv = __uint_as_float((w & 0xFFFFu) << 16);
    float da = fabsf(dv);
    unsigned long long m = __ballot(da > 1e-4f && da < 10.f);
    if ((t & 63) == 0) wc[t >> 6] = __popcll(m);
    __syncthreads();
    const int isbf = (wc[0] + wc[1] + wc[2] + wc[3]) >= 128;
    if (blockIdx.x == 0 && t == 0) *flag = isbf;

    const int gi = blockIdx.x * 256 + t;
    // ---- cvt_x: [Nn][100] -> bf16 [Nn][128] ----
    if (gi < Nn * 128) {
        int row = gi >> 7, col = gi & 127;
        float v = (col < INF_) ? ld_any(x, row * INF_ + col, isbf) : 0.f;
        xb[gi] = __float2bfloat16(v);
    }
    // ---- weights -> packed transposed Wt[1280][128] ----
    if (gi < WROWS * 128) {
        int row = gi >> 7, k = gi & 127;
        float v = 0.f;
#pragma unroll
        for (int q = 0; q < 8; ++q) {
            if (row >= pt.row0[q] && row < pt.row0[q] + pt.MP[q]) {
                int mm = row - pt.row0[q];
                if (mm < pt.M[q] && k < pt.K[q])
                    v = ld_any(pt.src[q], k * pt.M[q] + mm, isbf);
            }
        }
        wtb[gi] = __float2bfloat16(v);
    }
    // ---- small params ----
    if (gi < tot) {
        int seg = 0;
        while (gi >= ct.off[seg + 1]) seg++;
        pb[gi] = __float2bfloat16(ld_any(ct.src[seg], gi - ct.off[seg], isbf));
    }
    // ---- pre-scaled src byte offsets ----
    if (gi < Ee) {
        unsigned s = (unsigned)src[gi];
        w384[gi] = s * 384u;  // stride HCP*2 bytes (layer-2 split-pack fs)
        w256[gi] = s << 8;    // stride HD*2 bytes  (layer-0/1 fs)
    }
    // ---- BN accumulator zeroing ----
    if (gi < 2 * HD) { z0[gi] = 0.f; z1[gi] = 0.f; }
    // ---- CSR ptr + block-local degree histogram ----
    if (blockIdx.x < NBLK) {
        int nn = gi;
        int lb = Ee;
        if (nn <= Nn) { lb = lbound(dst, nn); ptr[nn] = lb; }
        lbv[t] = lb;
        if (t == 255) lbv[256] = (nn + 1 <= Nn) ? lbound(dst, nn + 1) : Ee;
        lh[t] = 0;
        __syncthreads();
        if (nn < Nn) {
            int dg = lbv[t + 1] - lbv[t]; if (dg > 255) dg = 255;
            atomicAdd(&lh[dg], 1);
        }
        __syncthreads();
        cnt[t * NBLK + blockIdx.x] = lh[t];
    }
}

// ---------------- LPT plan: per-(bin,block) scatter bases in ONE kernel -----------
// 64 blocks x 4 waves; wave owns bin. Suffix-total over HIGHER-degree bins is
// recomputed on the fly from cnt (400KB, L2-hot) - replaces the separate
// deg_totals launch. Then chunked 64-lane exclusive prefix over the NBLK
// per-block counts. (Math identical to the r11 two-kernel pair.)
__global__ void deg_plan(const int* __restrict__ cnt, int* __restrict__ base) {
    int wave = threadIdx.x >> 6, lane = threadIdx.x & 63;
    int bin = blockIdx.x * 4 + wave;
    int bb = 0;
    for (int b = bin + 1; b < 256; ++b)
        for (int k = lane; k < NBLK; k += 64) bb += cnt[b * NBLK + k];
#pragma unroll
    for (int o = 1; o < 64; o <<= 1) bb += __shfl_xor(bb, o);
    int run = bb;   // descending-degree base for this bin
    for (int k0 = 0; k0 < NBLK; k0 += 64) {
        int k = k0 + lane;
        int c = (k < NBLK) ? cnt[bin * NBLK + k] : 0;
        int p = c;
#pragma unroll
        for (int o = 1; o < 64; o <<= 1) {
            int t = __shfl_up(p, o);
            if (lane >= o) p += t;
        }
        if (k < NBLK) base[bin * NBLK + k] = run + (p - c);
        run += __shfl(p, 63);
    }
}

__global__ void deg_scatter_blk(const int* __restrict__ ptr, const int* __restrict__ base,
                                int* __restrict__ perm) {
    __shared__ int lh[256];
    int t = threadIdx.x;
    lh[t] = 0;
    __syncthreads();
    int n = blockIdx.x * 256 + t;
    if (n < Nn) {
        int dg = ptr[n + 1] - ptr[n]; if (dg > 255) dg = 255;
        int loc = atomicAdd(&lh[dg], 1);   // LDS atomic: one CU, cheap
        perm[base[dg * NBLK + blockIdx.x] + loc] = n;
    }
}

// ---------------- big-tile MFMA GEMM: 64 rows x (64*CS) cols per block -------------
// y-grid column split (deep grid hides store latency; NY-in-kernel regressed).
// LDS-staged COALESCED epilogue. PACK (layer-2 SPLIT layout): col lc -> h=lc/47,
// cc=lc%47, j=cc&15, k=cc>>4, lane l=16h+j; k<2 -> elem 2l+k (dword zone,
// bytes 0..255); k=2 -> elem 128+l (ushort zone, bytes 256..383). 384B row,
// zero traffic overhead; gat_188 needs only 2 gathers/edge.
template <int MP, int NOUT, int CS, bool ABN, bool PACK, int OSTR>
__global__ __launch_bounds__(256, 4) void gemm_big(
    const bf16* __restrict__ A, const bf16* __restrict__ Wt,
    const bf16* __restrict__ b0, const bf16* __restrict__ b1,
    const bf16* __restrict__ b2,
    bf16* __restrict__ o0, bf16* __restrict__ o1, bf16* __restrict__ o2,
    int MR, const float* __restrict__ sums,
    const bf16* __restrict__ gg, const bf16* __restrict__ bbn) {
    constexpr int CS64 = CS * 64;
    constexpr int PITCH = CS64 + 8;                 // 16B-aligned row stride
    constexpr int LSZ = (64 * PITCH > 64 * 136) ? 64 * PITCH : 64 * 136;
    __shared__ __align__(16) bf16 Al[LSZ];
    __shared__ float scb[ABN ? HD : 1], ofb[ABN ? HD : 1];
    const int row0 = blockIdx.x * 64;
    const int tid = threadIdx.x;
    if (ABN) {
        if (tid < HD) {
            float mu = sums[tid] * (1.f / Nn);
            float var = sums[HD + tid] * (1.f / Nn) - mu * mu;
            float sc = tof(gg[tid]) * rsqrtf(var + EPSV);
            scb[tid] = sc;
            ofb[tid] = tof(bbn[tid]) - mu * sc;
        }
        __syncthreads();
    }
#pragma unroll
    for (int j = 0; j < 4; ++j) {
        int idx = tid + j * 256;          // 0..1023 int4 slots
        int r = idx >> 4, kk = (idx & 15) * 8;
        int4 val = {0, 0, 0, 0};
        if (row0 + r < Nn) {
            val = *(const int4*)&A[(size_t)(row0 + r) * 128 + kk];
            if (ABN) {
                short8 av = *(short8*)&val;
                bf16 tmp[8];
#pragma unroll
                for (int u = 0; u < 8; ++u) {
                    float v = b2f((unsigned short)av[u]);
                    v = fmaxf(fmaf(v, scb[kk + u], ofb[kk + u]), 0.f);
                    tmp[u] = __float2bfloat16(v);
                }
                val = *(int4*)tmp;
            }
        }
        *(int4*)&Al[r * 136 + kk] = val;
    }
    __syncthreads();
    const int wave = tid >> 6, lane = tid & 63;
    const int n16 = lane & 15, quad = lane >> 4;
    const int colbase = blockIdx.y * CS64 + wave * (16 * CS);
    f32x4 acc[4][CS];
#pragma unroll
    for (int rt = 0; rt < 4; ++rt)
#pragma unroll
        for (int c = 0; c < CS; ++c) acc[rt][c] = (f32x4){0.f, 0.f, 0.f, 0.f};
    const bf16* wb[CS];
#pragma unroll
    for (int c = 0; c < CS; ++c)
        wb[c] = Wt + (size_t)(colbase + c * 16 + n16) * 128 + quad * 8;
    const bf16* ap = Al + n16 * 136 + quad * 8;
#pragma unroll
    for (int ks = 0; ks < 4; ++ks) {
        short8 bf[CS];
#pragma unroll
        for (int c = 0; c < CS; ++c) bf[c] = *(const short8*)(wb[c] + ks * 32);
#pragma unroll
        for (int rt = 0; rt < 4; ++rt) {
            short8 af = *(const short8*)(ap + rt * 16 * 136 + ks * 32);
#pragma unroll
            for (int c = 0; c < CS; ++c)
                acc[rt][c] = __builtin_amdgcn_mfma_f32_16x16x32_bf16(af, bf[c], acc[rt][c], 0, 0, 0);
        }
    }
    // ---- stage epilogue: Al reads done, reuse as [64][PITCH] ----
    __syncthreads();
    if (PACK) {   // zero pad slots (ushort-zone j=15 lanes + pitch cols)
        for (int z = tid; z < 64 * PITCH; z += 256) Al[z] = __float2bfloat16(0.f);
        __syncthreads();
    }
#pragma unroll
    for (int c = 0; c < CS; ++c) {
        int pos = wave * (16 * CS) + c * 16 + n16;    // within-block col
        int col = colbase + c * 16 + n16;
        int oi = col / MP, lc = col - oi * MP;
        bool valid = (oi < NOUT) && (lc < MR);
        float bb = 0.f;
        if (valid) {
            const bf16* bp = (oi == 0) ? b0 : (oi == 1) ? b1 : b2;
            bb = tof(bp[lc]);
        }
        int stp;
        if (PACK) {
            int hh = lc / 47, cc2 = lc - hh * 47;
            int jj = cc2 & 15, kk2 = cc2 >> 4;
            int l = hh * 16 + jj;
            stp = (kk2 < 2) ? (2 * l + kk2) : (128 + l);
        } else {
            stp = pos;
        }
#pragma unroll
        for (int rt = 0; rt < 4; ++rt) {
#pragma unroll
            for (int i = 0; i < 4; ++i) {
                int rl = rt * 16 + quad * 4 + i;
                if (valid) Al[rl * PITCH + stp] = __float2bfloat16(acc[rt][c][i] + bb);
            }
        }
    }
    __syncthreads();
    // ---- coalesced store: 8-elem (16B) groups; PACK stage IS the split layout ----
    constexpr int NG = CS64 / 8;
    for (int t = tid; t < 64 * NG; t += 256) {
        int rl = t / NG, g = t % NG;
        int row = row0 + rl;
        if (row >= Nn) continue;
        int pos0 = g * 8;
        int oi, lc0;
        if (PACK) { oi = blockIdx.y; lc0 = pos0; }    // y-block = full oi zone
        else {
            int col0 = blockIdx.y * CS64 + pos0;      // 8-group within one oi
            oi = col0 / MP; lc0 = col0 - oi * MP;
        }
        if (oi >= NOUT) continue;
        bf16* o = (oi == 0) ? o0 : (oi == 1) ? o1 : o2;
        int4 v = *(int4*)&Al[rl * PITCH + pos0];
        *(int4*)&o[(size_t)row * OSTR + lc0] = v;
    }
}

// ---------------- fused GATv2 edge kernel, M=128 (layers 0,1) ----------------
// 256 threads = 4 dsts/block. Lane holds cols (2*lane, 2*lane+1). MAX-FREE
// softmax, log2e folded into attn. Packed-FP32 math. srcW loads are WAVE-
// UNIFORM -> s_load (near-free); NO alignment peel.
template <bool RESBN>
__global__ __launch_bounds__(256) void gat_fused_128(
    const bf16* __restrict__ fs, const bf16* __restrict__ fd,
    const unsigned* __restrict__ srcW, const int* __restrict__ ptr,
    const int* __restrict__ perm,
    const bf16* __restrict__ attn, const bf16* __restrict__ resb,
    const float* __restrict__ sums, const bf16* __restrict__ gv,
    const bf16* __restrict__ bev, bf16* __restrict__ hout) {
    const int wave = threadIdx.x >> 6, lane = threadIdx.x & 63;
    const int di = blockIdx.x * 4 + wave;
    if (di >= Nn) return;
    const int d = perm[di];
    const int c0 = lane * 2;
    const unsigned c0b = (unsigned)c0 * 2u;
    ushort2 aq = *(const ushort2*)&attn[c0];
    float a0 = b2f(aq.x) * L2E, a1 = b2f(aq.y) * L2E;
    const f32x2 Av = pk2(0.6f * a0, 0.6f * a1);
    const f32x2 Bv = pk2(0.4f * a0, 0.4f * a1);
    ushort2 dq = *(const ushort2*)&fd[(size_t)d * HD + c0];
    const f32x2 fdv = pk2(b2f(dq.x), b2f(dq.y));
    const char* fsb = (const char*)fs;
    float l = 0.f;
    f32x2 Ov = pk2(0.f, 0.f);
    int e = ptr[d];
    const int e1 = ptr[d + 1];
    for (; e + 3 < e1; e += 4) {
        unsigned vA = srcW[e] + c0b, vB = srcW[e + 1] + c0b;
        unsigned vC = srcW[e + 2] + c0b, vD = srcW[e + 3] + c0b;
        ushort2 qA = *(const ushort2*)(fsb + vA);
        ushort2 qB = *(const ushort2*)(fsb + vB);
        ushort2 qC = *(const ushort2*)(fsb + vC);
        ushort2 qD = *(const ushort2*)(fsb + vD);
        f32x2 fA = pk2(b2f(qA.x), b2f(qA.y));
        f32x2 fB = pk2(b2f(qB.x), b2f(qB.y));
        f32x2 fC = pk2(b2f(qC.x), b2f(qC.y));
        f32x2 fD = pk2(b2f(qD.x), b2f(qD.y));
        f32x2 xA = fA + fdv, xB = fB + fdv, xC = fC + fdv, xD = fD + fdv;
        f32x2 tA = pfma2(pabs2(xA), Bv, xA * Av);
        f32x2 tB = pfma2(pabs2(xB), Bv, xB * Av);
        f32x2 tC = pfma2(pabs2(xC), Bv, xC * Av);
        f32x2 tD = pfma2(pabs2(xD), Bv, xD * Av);
        float pA = tA.x + tA.y, pB = tB.x + tB.y;
        float pC = tC.x + tC.y, pD = tD.x + tD.y;
        pA = sum16(pA); pB = sum16(pB); pC = sum16(pC); pD = sum16(pD);
        float eA = __builtin_amdgcn_exp2f(pA), eB = __builtin_amdgcn_exp2f(pB);
        float eC = __builtin_amdgcn_exp2f(pC), eD = __builtin_amdgcn_exp2f(pD);
        l += (eA + eB) + (eC + eD);
        Ov = pfma2(pk2(eA, eA), fA, Ov);
        Ov = pfma2(pk2(eB, eB), fB, Ov);
        Ov = pfma2(pk2(eC, eC), fC, Ov);
        Ov = pfma2(pk2(eD, eD), fD, Ov);
    }
    for (; e < e1; ++e) {
        unsigned v = srcW[e] + c0b;
        ushort2 fq = *(const ushort2*)(fsb + v);
        f32x2 f = pk2(b2f(fq.x), b2f(fq.y));
        f32x2 x = f + fdv;
        f32x2 t = pfma2(pabs2(x), Bv, x * Av);
        float p = sum16(t.x + t.y);
        float pe = __builtin_amdgcn_exp2f(p);
        l += pe;
        Ov = pfma2(pk2(pe, pe), f, Ov);
    }
    float inv = l > 0.f ? 1.f / l : 0.f;
    ushort2 rq = *(const ushort2*)&resb[(size_t)d * HD + c0];
    float r0 = b2f(rq.x), r1 = b2f(rq.y);
    if (RESBN) {
        float mu0 = sums[c0] * (1.f / Nn), mu1 = sums[c0 + 1] * (1.f / Nn);
        float va0 = sums[HD + c0] * (1.f / Nn) - mu0 * mu0;
        float va1 = sums[HD + c0 + 1] * (1.f / Nn) - mu1 * mu1;
        float sc0 = tof(gv[c0]) * rsqrtf(va0 + EPSV);
        float sc1 = tof(gv[c0 + 1]) * rsqrtf(va1 + EPSV);
        float of0 = tof(bev[c0]) - mu0 * sc0;
        float of1 = tof(bev[c0 + 1]) - mu1 * sc1;
        r0 = fmaxf(fmaf(r0, sc0, of0), 0.f);
        r1 = fmaxf(fmaf(r1, sc1, of1), 0.f);
    }
    float v0 = fmaxf(fmaf(Ov.x, inv, r0), 0.f);  // conv activation relu
    float v1 = fmaxf(fmaf(Ov.y, inv, r1), 0.f);
    ushort2 ov; ov.x = f2u(v0); ov.y = f2u(v1);
    *(ushort2*)&hout[(size_t)d * HD + c0] = ov;
}

// ---------------- fused GATv2 edge kernel, layer 2, SPLIT-PACK stride 192 --------
// Lane l=16h+j owns cc {j, j+16} as ONE dword at byte 4l and {j+32} as ONE
// ushort at byte 256+2l (2 gathers/edge; same 384B row = same FETCH).
// Scalar fmaf chain; scalar uniform srcW (s_load); NO alignment peel.
__global__ __launch_bounds__(256) void gat_fused_188(
    const bf16* __restrict__ fs, const bf16* __restrict__ fd,
    const unsigned* __restrict__ srcW, const int* __restrict__ ptr,
    const int* __restrict__ perm,
    const bf16* __restrict__ attn, const bf16* __restrict__ rs,
    void* __restrict__ out, const int* __restrict__ flag) {
    const int wave = threadIdx.x >> 6, lane = threadIdx.x & 63;
    const int di = blockIdx.x * 4 + wave;
    if (di >= Nn) return;
    const int d = perm[di];
    const int h = lane >> 4, j = lane & 15;
    const unsigned cbA = (unsigned)lane * 4u;          // dword zone
    const unsigned cbB = 256u + (unsigned)lane * 2u;   // ushort zone
    const int ca = h * Cc + j;                         // attn is unpadded [188]
    const bool has2 = (j < 15);
    float a0 = ldb(&attn[ca]) * L2E;
    float a1 = ldb(&attn[ca + 16]) * L2E;
    float a2 = has2 ? ldb(&attn[ca + 32]) * L2E : 0.f;
    float A0 = 0.6f * a0, B0 = 0.4f * a0;
    float A1 = 0.6f * a1, B1 = 0.4f * a1;
    float A2 = 0.6f * a2, B2 = 0.4f * a2;
    const char* fdb = (const char*)fd;
    const size_t drow = (size_t)d * 384u;
    unsigned dqa = *(const unsigned*)(fdb + drow + cbA);
    unsigned short dqb = *(const unsigned short*)(fdb + drow + cbB);
    float fd0 = b2flo(dqa), fd1 = b2fhi(dqa);
    float fd2 = b2f(dqb);   // j=15: zero-filled pad, A2=B2=0 masks
    const char* fsb = (const char*)fs;
    float l = 0.f, O0 = 0.f, O1 = 0.f, O2 = 0.f;
    int e = ptr[d];
    const int e1 = ptr[d + 1];
    for (; e + 3 < e1; e += 4) {
        unsigned bA = srcW[e], bB = srcW[e + 1], bC = srcW[e + 2], bD = srcW[e + 3];
        unsigned qA = *(const unsigned*)(fsb + bA + cbA);
        unsigned qB = *(const unsigned*)(fsb + bB + cbA);
        unsigned qC = *(const unsigned*)(fsb + bC + cbA);
        unsigned qD = *(const unsigned*)(fsb + bD + cbA);
        unsigned short uA = *(const unsigned short*)(fsb + bA + cbB);
        unsigned short uB = *(const unsigned short*)(fsb + bB + cbB);
        unsigned short uC = *(const unsigned short*)(fsb + bC + cbB);
        unsigned short uD = *(const unsigned short*)(fsb + bD + cbB);
        float fA0 = b2flo(qA), fA1 = b2fhi(qA), fA2 = b2f(uA);
        float fB0 = b2flo(qB), fB1 = b2fhi(qB), fB2 = b2f(uB);
        float fC0 = b2flo(qC), fC1 = b2fhi(qC), fC2 = b2f(uC);
        float fD0 = b2flo(qD), fD1 = b2fhi(qD), fD2 = b2f(uD);
        float xA0 = fA0 + fd0, xA1 = fA1 + fd1, xA2 = fA2 + fd2;
        float xB0 = fB0 + fd0, xB1 = fB1 + fd1, xB2 = fB2 + fd2;
        float xC0 = fC0 + fd0, xC1 = fC1 + fd1, xC2 = fC2 + fd2;
        float xD0 = fD0 + fd0, xD1 = fD1 + fd1, xD2 = fD2 + fd2;
        float pA = fmaf(xA0, A0, fmaf(fabsf(xA0), B0, fmaf(xA1, A1, fmaf(fabsf(xA1), B1,
                   fmaf(xA2, A2, fabsf(xA2) * B2)))));
        float pB = fmaf(xB0, A0, fmaf(fabsf(xB0), B0, fmaf(xB1, A1, fmaf(fabsf(xB1), B1,
                   fmaf(xB2, A2, fabsf(xB2) * B2)))));
        float pC = fmaf(xC0, A0, fmaf(fabsf(xC0), B0, fmaf(xC1, A1, fmaf(fabsf(xC1), B1,
                   fmaf(xC2, A2, fabsf(xC2) * B2)))));
        float pD = fmaf(xD0, A0, fmaf(fabsf(xD0), B0, fmaf(xD1, A1, fmaf(fabsf(xD1), B1,
                   fmaf(xD2, A2, fabsf(xD2) * B2)))));
        pA = sum16(pA); pB = sum16(pB); pC = sum16(pC); pD = sum16(pD);
        float eA = __builtin_amdgcn_exp2f(pA), eB = __builtin_amdgcn_exp2f(pB);
        float eC = __builtin_amdgcn_exp2f(pC), eD = __builtin_amdgcn_exp2f(pD);
        l += (eA + eB) + (eC + eD);
        O0 = fmaf(eA, fA0, O0); O0 = fmaf(eB, fB0, O0);
        O0 = fmaf(eC, fC0, O0); O0 = fmaf(eD, fD0, O0);
        O1 = fmaf(eA, fA1, O1); O1 = fmaf(eB, fB1, O1);
        O1 = fmaf(eC, fC1, O1); O1 = fmaf(eD, fD1, O1);
        O2 = fmaf(eA, fA2, O2); O2 = fmaf(eB, fB2, O2);
        O2 = fmaf(eC, fC2, O2); O2 = fmaf(eD, fD2, O2);
    }
    for (; e < e1; ++e) {
        unsigned b = srcW[e];
        unsigned q = *(const unsigned*)(fsb + b + cbA);
        unsigned short u = *(const unsigned short*)(fsb + b + cbB);
        float f0 = b2flo(q), f1 = b2fhi(q), f2 = b2f(u);
        float x0 = f0 + fd0, x1 = f1 + fd1, x2 = f2 + fd2;
        float p = fmaf(x0, A0, fmaf(fabsf(x0), B0, fmaf(x1, A1, fmaf(fabsf(x1), B1,
                  fmaf(x2, A2, fabsf(x2) * B2)))));
        p = sum16(p);
        float pe = __builtin_amdgcn_exp2f(p);
        l += pe;
        O0 = fmaf(pe, f0, O0);
        O1 = fmaf(pe, f1, O1);
        O2 = fmaf(pe, f2, O2);
    }
    // epilogue: +res, head-mean across lane groups, log_softmax, store
    float inv = l > 0.f ? 1.f / l : 0.f;
    const char* rb_ = (const char*)rs;
    unsigned rqa = *(const unsigned*)(rb_ + drow + cbA);
    unsigned short rqb = *(const unsigned short*)(rb_ + drow + cbB);
    float v0 = fmaf(O0, inv, b2flo(rqa));
    float v1 = fmaf(O1, inv, b2fhi(rqa));
    float v2 = has2 ? fmaf(O2, inv, b2f(rqb)) : 0.f;
    v0 += __shfl_xor(v0, 16); v0 += __shfl_xor(v0, 32); v0 *= 0.25f;
    v1 += __shfl_xor(v1, 16); v1 += __shfl_xor(v1, 32); v1 *= 0.25f;
    v2 += __shfl_xor(v2, 16); v2 += __shfl_xor(v2, 32); v2 *= 0.25f;
    float mx = fmaxf(v0, v1);
    if (has2) mx = fmaxf(mx, v2);
    mx = max16(mx);
    float sm = __expf(v0 - mx) + __expf(v1 - mx) + (has2 ? __expf(v2 - mx) : 0.f);
    sm = sum16(sm);
    if (h == 0) {
        float ls = mx + __log2f(sm) * LN2;
        if (*flag) {
            bf16* o = (bf16*)out + (size_t)d * Cc;
            o[j] = __float2bfloat16(v0 - ls);
            o[j + 16] = __float2bfloat16(v1 - ls);
            if (has2) o[j + 32] = __float2bfloat16(v2 - ls);
        } else {
            float* o = (float*)out + (size_t)d * Cc;
            o[j] = v0 - ls;
            o[j + 16] = v1 - ls;
            if (has2) o[j + 32] = v2 - ls;
        }
    }
}

// ---------------- per-column BN stats over bf16 h (atomic combine) ----------------
// 391 blocks x 64 threads (ONE wave); thread c owns col pair (2c,2c+1) via
// ushort2 loads -> 64 lanes x 4B = full 256B-row coalescing. Indices stay
// within sums[0..255]. ONE atomicAdd per thread per stat. (r12 bug: this body
// launched with 128 threads read past row end and wrote OOB into params.)
__global__ void col_stats(const bf16* __restrict__ in, float* __restrict__ sums) {
    int c = threadIdx.x;  // 64 threads -> cols (2c, 2c+1), 2c in [0,126]
    int r0 = blockIdx.x * 256;
    int r1 = r0 + 256; if (r1 > Nn) r1 = Nn;
    float s0 = 0.f, s1 = 0.f, q0 = 0.f, q1 = 0.f;
    for (int r = r0; r < r1; ++r) {
        ushort2 v = *(const ushort2*)&in[(size_t)r * HD + 2 * c];
        float a = b2f(v.x), b = b2f(v.y);
        s0 += a; q0 = fmaf(a, a, q0);
        s1 += b; q1 = fmaf(b, b, q1);
    }
    atomicAdd(&sums[2 * c], s0);
    atomicAdd(&sums[2 * c + 1], s1);
    atomicAdd(&sums[HD + 2 * c], q0);
    atomicAdd(&sums[HD + 2 * c + 1], q1);
}

extern "C" void kernel_launch(void* const* d_in, const int* in_sizes, int n_in,
                              void* d_out, int out_size, void* d_ws, size_t ws_size,
                              hipStream_t stream) {
    (void)in_sizes; (void)n_in; (void)out_size; (void)ws_size;
    const void* x = d_in[0];
    const int* src = (const int*)d_in[1];
    const int* dst = (const int*)d_in[2];

    char* ws = (char*)d_ws;
    size_t off = 0;
    auto alloc = [&](size_t bytes) {
        void* p = ws + off;
        off += (bytes + 255) & ~(size_t)255;
        return p;
    };
    // rs (38.4 MB, [Nn][192]) aliases xb+rb (51.2 MB): both dead before L2 GEMM.
    bf16* xb = (bf16*)alloc((size_t)Nn * 128 * 2);    // 25.6 MB (stride-128 padded x)
    bf16* rb = (bf16*)alloc((size_t)Nn * HD * 2);     // 25.6 MB
    bf16* rs = xb;                                    // [Nn][HCP] alias
    bf16* fs = (bf16*)alloc((size_t)Nn * HCP * 2);    // 38.4 MB
    bf16* fd = (bf16*)alloc((size_t)Nn * HCP * 2);    // 38.4 MB
    bf16* hbA = (bf16*)alloc((size_t)Nn * HD * 2);    // 25.6 MB
    bf16* hbB = (bf16*)alloc((size_t)Nn * HD * 2);    // 25.6 MB
    int* ptr = (int*)alloc((Nn + 1) * 4);             // 400 KB
    bf16* wtb = (bf16*)alloc((size_t)WROWS * 128 * 2);// 328 KB
    float* bns0 = (float*)alloc(2 * HD * 4);
    float* bns1 = (float*)alloc(2 * HD * 4);
    bf16* pb = (bf16*)alloc(4096 * 2);
    int* flag = (int*)alloc(256);
    unsigned* w384 = (unsigned*)alloc((size_t)Ee * 4);// 4 MB
    unsigned* w256 = (unsigned*)alloc((size_t)Ee * 4);// 4 MB
    int* cnt = (int*)alloc((size_t)256 * NBLK * 4);   // 400 KB
    int* cbase = (int*)alloc((size_t)256 * NBLK * 4); // 400 KB
    int* perm = (int*)alloc((size_t)Nn * 4);          // 400 KB

    // ---- small-param conversion (biases/attn/bn): d_in idx -> pb arena ----
    static const int spIdx[NSP] = {4, 6, 7, 9, 11, 13, 14, 16, 18, 19, 21, 22, 23, 24, 25};
    static const int spSz[NSP]  = {HD, HD, HD, HD, HD, HD, HD, HC, HC, HC, HC, HD, HD, HD, HD};
    CvtTab tab;
    int tot = 0;
    for (int i = 0; i < NSP; ++i) { tab.src[i] = d_in[spIdx[i]]; tab.off[i] = tot; tot += spSz[i]; }
    tab.off[NSP] = tot;
    const bf16 *bsrc0 = pb + tab.off[0], *bdst0 = pb + tab.off[1], *attn0 = pb + tab.off[2],
               *bres0 = pb + tab.off[3], *bsrc1 = pb + tab.off[4], *bdst1 = pb + tab.off[5],
               *attn1 = pb + tab.off[6], *bsrc2 = pb + tab.off[7], *bdst2 = pb + tab.off[8],
               *attn2 = pb + tab.off[9], *bres2 = pb + tab.off[10],
               *g0 = pb + tab.off[11], *be0 = pb + tab.off[12],
               *g1 = pb + tab.off[13], *be1 = pb + tab.off[14];

    // ---- packed Wt: rows [0,384)=L0, [384,640)=L1, [640,1216)=L2 @MP=192, pad->1280 ----
    PrepTab pt;
    static const int wIdx[8] = {3, 5, 8, 10, 12, 15, 17, 20};
    static const int wK[8]   = {INF_, INF_, INF_, HD, HD, HD, HD, HD};
    static const int wM[8]   = {HD, HD, HD, HD, HD, HC, HC, HC};
    static const int wMP[8]  = {128, 128, 128, 128, 128, 192, 192, 192};
    static const int wR0[8]  = {0, 128, 256, 384, 512, 640, 832, 1024};
    for (int i = 0; i < 8; ++i) {
        pt.src[i] = d_in[wIdx[i]]; pt.row0[i] = wR0[i];
        pt.K[i] = wK[i]; pt.M[i] = wM[i]; pt.MP[i] = wMP[i];
    }

    // ---- mega prepare (detect + cvt_x + weights + params + src offsets + ptr/hist) --
    const int prepGrid = (Nn * 128 + 255) / 256;   // 50000 blocks, covers all jobs
    prepare<<<prepGrid, 256, 0, stream>>>(x, src, dst, pt, tab, tot,
                                          xb, wtb, pb, w384, w256, ptr, cnt,
                                          bns0, bns1, flag);
    deg_plan<<<64, 256, 0, stream>>>(cnt, cbase);
    deg_scatter_blk<<<NBLK, 256, 0, stream>>>(ptr, cbase, perm);

    const int fusedGrid = (Nn + 3) / 4;   // 256-thread blocks, 4 dsts each
    const int statsGrid = NBLK;
    const int rowBlk = (Nn + 63) / 64;  // 1563

    // ---------------- layer 0 (384 cols: y=2 x CS=3) ----------------
    gemm_big<128, 3, 3, false, false, HD><<<dim3(rowBlk, 2), 256, 0, stream>>>(
        xb, wtb, bsrc0, bdst0, bres0, fs, fd, rb, HD, nullptr, nullptr, nullptr);
    gat_fused_128<false><<<fusedGrid, 256, 0, stream>>>(fs, fd, w256, ptr, perm,
                                                        attn0, rb, nullptr, nullptr,
                                                        nullptr, hbA);
    col_stats<<<statsGrid, 64, 0, stream>>>(hbA, bns0);

    // ---------------- layer 1 (256 cols: y=2 x CS=2) ----------------
    gemm_big<128, 2, 2, true, false, HD><<<dim3(rowBlk, 2), 256, 0, stream>>>(
        hbA, wtb + (size_t)384 * 128, bsrc1, bdst1, nullptr, fs, fd, nullptr, HD,
        bns0, g0, be0);
    gat_fused_128<true><<<fusedGrid, 256, 0, stream>>>(fs, fd, w256, ptr, perm,
                                                       attn1, hbA, bns0, g0, be0, hbB);
    col_stats<<<statsGrid, 64, 0, stream>>>(hbB, bns1);

    // ---------------- layer 2 (576 cols: y=3 x CS=3, split-pack coalesced outputs) --
    gemm_big<192, 3, 3, true, true, HCP><<<dim3(rowBlk, 3), 256, 0, stream>>>(
        hbB, wtb + (size_t)640 * 128, bsrc2, bdst2, bres2, fs, fd, rs, HC,
        bns1, g1, be1);
    gat_fused_188<<<fusedGrid, 256, 0, stream>>>(fs, fd, w384, ptr, perm, attn2, rs,
                                                 d_out, flag);
}

// Round 14
// 650.410 us; speedup vs baseline: 1.2820x; 1.2820x over previous
//
#include <hip/hip_runtime.h>
#include <hip/hip_bf16.h>

#define Nn 100000
#define Ee 1000000
#define INF_ 100
#define Hh 4
#define Dd 32
#define HD 128
#define Cc 47
#define HC 188
#define HCP 192
#define EPSV 1e-5f
#define SLOPE 0.2f
#define NBLK ((Nn + 255) / 256)

typedef __hip_bfloat16 bf16;
typedef __attribute__((ext_vector_type(8))) short short8;
typedef __attribute__((ext_vector_type(4))) float f32x4;
typedef __attribute__((ext_vector_type(2))) float f32x2;

__device__ __forceinline__ float tof(bf16 v) { return __bfloat162float(v); }
__device__ __forceinline__ float b2f(unsigned short u) {
    return __uint_as_float((unsigned)u << 16);
}
__device__ __forceinline__ float b2flo(unsigned u) {
    return __uint_as_float(u << 16);
}
__device__ __forceinline__ float b2fhi(unsigned u) {
    return __uint_as_float(u & 0xFFFF0000u);
}
__device__ __forceinline__ float ldb(const bf16* p) {
    return b2f(*(const unsigned short*)p);
}
__device__ __forceinline__ unsigned short f2u(float v) {
    bf16 t = __float2bfloat16(v);
    return *(unsigned short*)&t;
}
__device__ __forceinline__ f32x2 pk2(float x, float y) {
    f32x2 r; r.x = x; r.y = y; return r;
}
__device__ __forceinline__ f32x2 pabs2(f32x2 v) {          // v_pk_max_f32 v, -v
    return __builtin_elementwise_max(v, -v);
}
__device__ __forceinline__ f32x2 pfma2(f32x2 a, f32x2 b, f32x2 c) {
    return __builtin_elementwise_fma(a, b, c);             // v_pk_fma_f32
}

// DPP-fused 16-lane reduces (quad_perm swaps + row rotates; row=16 lanes).
template <int C>
__device__ __forceinline__ float dppadd(float v) {
    int m = __builtin_amdgcn_update_dpp(0, __float_as_int(v), C, 0xF, 0xF, false);
    return v + __int_as_float(m);
}
template <int C>
__device__ __forceinline__ float dppmax(float v) {
    int m = __builtin_amdgcn_update_dpp(0, __float_as_int(v), C, 0xF, 0xF, false);
    return fmaxf(v, __int_as_float(m));
}
__device__ __forceinline__ float sum16(float p) {
    p = dppadd<0xB1>(p);   // quad_perm [1,0,3,2]
    p = dppadd<0x4E>(p);   // quad_perm [2,3,0,1]
    p = dppadd<0x124>(p);  // row_ror:4
    p = dppadd<0x128>(p);  // row_ror:8
    return p;
}
__device__ __forceinline__ float max16(float p) {
    p = dppmax<0xB1>(p); p = dppmax<0x4E>(p);
    p = dppmax<0x124>(p); p = dppmax<0x128>(p);
    return p;
}

#define L2E 1.4426950408889634f
#define LN2 0.6931471805599453f

__device__ __forceinline__ float ld_any(const void* p, int i, int isbf) {
    return isbf ? tof(((const bf16*)p)[i]) : ((const float*)p)[i];
}

__device__ __forceinline__ int lbound(const int* __restrict__ dst, int n) {
    int lo = 0, hi = Ee;
    while (lo < hi) {
        int mid = (lo + hi) >> 1;
        if (dst[mid] < n) lo = mid + 1; else hi = mid;
    }
    return lo;
}

// ---------------- MEGA prepare kernel ----------------
// Each block independently derives the dtype flag (ballot over x[0..255] words,
// L2-hot, deterministic) -> no cross-kernel flag dependency. Jobs partitioned
// by global index: cvt_x | weight pack | small params | src byte-offsets |
// bns zeroing | CSR ptr + BLOCK-LOCAL degree histogram (lower_bounds shared
// through LDS so hist needs no globally-complete ptr).
#define WROWS 1280
#define NSP 15
struct PrepTab { const void* src[8]; int row0[8]; int K[8]; int M[8]; int MP[8]; };
struct CvtTab { const void* src[NSP]; int off[NSP + 1]; };

__global__ __launch_bounds__(256) void prepare(
    const void* __restrict__ x, const int* __restrict__ src,
    const int* __restrict__ dst,
    PrepTab pt, CvtTab ct, int tot,
    bf16* __restrict__ xb, bf16* __restrict__ wtb, bf16* __restrict__ pb,
    unsigned* __restrict__ w384, unsigned* __restrict__ w256,
    int* __restrict__ ptr, int* __restrict__ cnt,
    float* __restrict__ z0, float* __restrict__ z1, int* __restrict__ flag) {
    __shared__ int wc[4];
    __shared__ int lbv[257];
    __shared__ int lh[256];
    const int t = threadIdx.x;
    // ---- per-block dtype detect ----
    unsigned w = ((const unsigned*)x)[t];
    float dv = __uint_as_float((w & 0xFFFFu) << 16);
    float da = fabsf(dv);
    unsigned long long m = __ballot(da > 1e-4f && da < 10.f);
    if ((t & 63) == 0) wc[t >> 6] = __popcll(m);
    __syncthreads();
    const int isbf = (wc[0] + wc[1] + wc[2] + wc[3]) >= 128;
    if (blockIdx.x == 0 && t == 0) *flag = isbf;

    const int gi = blockIdx.x * 256 + t;
    // ---- cvt_x: [Nn][100] -> bf16 [Nn][128] ----
    if (gi < Nn * 128) {
        int row = gi >> 7, col = gi & 127;
        float v = (col < INF_) ? ld_any(x, row * INF_ + col, isbf) : 0.f;
        xb[gi] = __float2bfloat16(v);
    }
    // ---- weights -> packed transposed Wt[1280][128] ----
    if (gi < WROWS * 128) {
        int row = gi >> 7, k = gi & 127;
        float v = 0.f;
#pragma unroll
        for (int q = 0; q < 8; ++q) {
            if (row >= pt.row0[q] && row < pt.row0[q] + pt.MP[q]) {
                int mm = row - pt.row0[q];
                if (mm < pt.M[q] && k < pt.K[q])
                    v = ld_any(pt.src[q], k * pt.M[q] + mm, isbf);
            }
        }
        wtb[gi] = __float2bfloat16(v);
    }
    // ---- small params ----
    if (gi < tot) {
        int seg = 0;
        while (gi >= ct.off[seg + 1]) seg++;
        pb[gi] = __float2bfloat16(ld_any(ct.src[seg], gi - ct.off[seg], isbf));
    }
    // ---- pre-scaled src byte offsets ----
    if (gi < Ee) {
        unsigned s = (unsigned)src[gi];
        w384[gi] = s * 384u;  // stride HCP*2 bytes (layer-2 split-pack fs)
        w256[gi] = s << 8;    // stride HD*2 bytes  (layer-0/1 fs)
    }
    // ---- BN accumulator zeroing ----
    if (gi < 2 * HD) { z0[gi] = 0.f; z1[gi] = 0.f; }
    // ---- CSR ptr + block-local degree histogram ----
    if (blockIdx.x < NBLK) {
        int nn = gi;
        int lb = Ee;
        if (nn <= Nn) { lb = lbound(dst, nn); ptr[nn] = lb; }
        lbv[t] = lb;
        if (t == 255) lbv[256] = (nn + 1 <= Nn) ? lbound(dst, nn + 1) : Ee;
        lh[t] = 0;
        __syncthreads();
        if (nn < Nn) {
            int dg = lbv[t + 1] - lbv[t]; if (dg > 255) dg = 255;
            atomicAdd(&lh[dg], 1);
        }
        __syncthreads();
        cnt[t * NBLK + blockIdx.x] = lh[t];
    }
}

// ---------------- degree-descending LPT permutation -------------------------------
// TWO kernels, deliberately: fusing the suffix-total into deg_bases made each
// wave run ~1800 serially-dependent loads at 1.6% occupancy (204us, r13).
// deg_totals spreads that work over 256 parallel waves (~6 coalesced loads each).
__global__ void deg_totals(const int* __restrict__ cnt, int* __restrict__ totals) {
    int wave = threadIdx.x >> 6, lane = threadIdx.x & 63;
    int bin = blockIdx.x * 4 + wave;
    int s = 0;
    for (int k = lane; k < NBLK; k += 64) s += cnt[bin * NBLK + k];
#pragma unroll
    for (int o = 1; o < 64; o <<= 1) s += __shfl_xor(s, o);
    if (lane == 0) totals[bin] = s;
}

// one wave per bin: binbase = sum of totals over HIGHER-degree bins (256 tiny
// loads, L2-hot), then chunked 64-lane exclusive prefix over per-block counts.
__global__ void deg_bases(const int* __restrict__ cnt, const int* __restrict__ totals,
                          int* __restrict__ base) {
    int wave = threadIdx.x >> 6, lane = threadIdx.x & 63;
    int bin = blockIdx.x * 4 + wave;
    int bb = 0;
    for (int b = bin + 1 + lane; b < 256; b += 64) bb += totals[b];
#pragma unroll
    for (int o = 1; o < 64; o <<= 1) bb += __shfl_xor(bb, o);
    int run = bb;   // descending-degree base for this bin
    for (int k0 = 0; k0 < NBLK; k0 += 64) {
        int k = k0 + lane;
        int c = (k < NBLK) ? cnt[bin * NBLK + k] : 0;
        int p = c;
#pragma unroll
        for (int o = 1; o < 64; o <<= 1) {
            int t = __shfl_up(p, o);
            if (lane >= o) p += t;
        }
        if (k < NBLK) base[bin * NBLK + k] = run + (p - c);
        run += __shfl(p, 63);
    }
}

__global__ void deg_scatter_blk(const int* __restrict__ ptr, const int* __restrict__ base,
                                int* __restrict__ perm) {
    __shared__ int lh[256];
    int t = threadIdx.x;
    lh[t] = 0;
    __syncthreads();
    int n = blockIdx.x * 256 + t;
    if (n < Nn) {
        int dg = ptr[n + 1] - ptr[n]; if (dg > 255) dg = 255;
        int loc = atomicAdd(&lh[dg], 1);   // LDS atomic: one CU, cheap
        perm[base[dg * NBLK + blockIdx.x] + loc] = n;
    }
}

// ---------------- big-tile MFMA GEMM: 64 rows x (64*CS) cols per block -------------
// y-grid column split (deep grid hides store latency; NY-in-kernel regressed).
// LDS-staged COALESCED epilogue. PACK (layer-2 SPLIT layout): col lc -> h=lc/47,
// cc=lc%47, j=cc&15, k=cc>>4, lane l=16h+j; k<2 -> elem 2l+k (dword zone,
// bytes 0..255); k=2 -> elem 128+l (ushort zone, bytes 256..383). 384B row,
// zero traffic overhead; gat_188 needs only 2 gathers/edge.
template <int MP, int NOUT, int CS, bool ABN, bool PACK, int OSTR>
__global__ __launch_bounds__(256, 4) void gemm_big(
    const bf16* __restrict__ A, const bf16* __restrict__ Wt,
    const bf16* __restrict__ b0, const bf16* __restrict__ b1,
    const bf16* __restrict__ b2,
    bf16* __restrict__ o0, bf16* __restrict__ o1, bf16* __restrict__ o2,
    int MR, const float* __restrict__ sums,
    const bf16* __restrict__ gg, const bf16* __restrict__ bbn) {
    constexpr int CS64 = CS * 64;
    constexpr int PITCH = CS64 + 8;                 // 16B-aligned row stride
    constexpr int LSZ = (64 * PITCH > 64 * 136) ? 64 * PITCH : 64 * 136;
    __shared__ __align__(16) bf16 Al[LSZ];
    __shared__ float scb[ABN ? HD : 1], ofb[ABN ? HD : 1];
    const int row0 = blockIdx.x * 64;
    const int tid = threadIdx.x;
    if (ABN) {
        if (tid < HD) {
            float mu = sums[tid] * (1.f / Nn);
            float var = sums[HD + tid] * (1.f / Nn) - mu * mu;
            float sc = tof(gg[tid]) * rsqrtf(var + EPSV);
            scb[tid] = sc;
            ofb[tid] = tof(bbn[tid]) - mu * sc;
        }
        __syncthreads();
    }
#pragma unroll
    for (int j = 0; j < 4; ++j) {
        int idx = tid + j * 256;          // 0..1023 int4 slots
        int r = idx >> 4, kk = (idx & 15) * 8;
        int4 val = {0, 0, 0, 0};
        if (row0 + r < Nn) {
            val = *(const int4*)&A[(size_t)(row0 + r) * 128 + kk];
            if (ABN) {
                short8 av = *(short8*)&val;
                bf16 tmp[8];
#pragma unroll
                for (int u = 0; u < 8; ++u) {
                    float v = b2f((unsigned short)av[u]);
                    v = fmaxf(fmaf(v, scb[kk + u], ofb[kk + u]), 0.f);
                    tmp[u] = __float2bfloat16(v);
                }
                val = *(int4*)tmp;
            }
        }
        *(int4*)&Al[r * 136 + kk] = val;
    }
    __syncthreads();
    const int wave = tid >> 6, lane = tid & 63;
    const int n16 = lane & 15, quad = lane >> 4;
    const int colbase = blockIdx.y * CS64 + wave * (16 * CS);
    f32x4 acc[4][CS];
#pragma unroll
    for (int rt = 0; rt < 4; ++rt)
#pragma unroll
        for (int c = 0; c < CS; ++c) acc[rt][c] = (f32x4){0.f, 0.f, 0.f, 0.f};
    const bf16* wb[CS];
#pragma unroll
    for (int c = 0; c < CS; ++c)
        wb[c] = Wt + (size_t)(colbase + c * 16 + n16) * 128 + quad * 8;
    const bf16* ap = Al + n16 * 136 + quad * 8;
#pragma unroll
    for (int ks = 0; ks < 4; ++ks) {
        short8 bf[CS];
#pragma unroll
        for (int c = 0; c < CS; ++c) bf[c] = *(const short8*)(wb[c] + ks * 32);
#pragma unroll
        for (int rt = 0; rt < 4; ++rt) {
            short8 af = *(const short8*)(ap + rt * 16 * 136 + ks * 32);
#pragma unroll
            for (int c = 0; c < CS; ++c)
                acc[rt][c] = __builtin_amdgcn_mfma_f32_16x16x32_bf16(af, bf[c], acc[rt][c], 0, 0, 0);
        }
    }
    // ---- stage epilogue: Al reads done, reuse as [64][PITCH] ----
    __syncthreads();
    if (PACK) {   // zero pad slots (ushort-zone j=15 lanes + pitch cols)
        for (int z = tid; z < 64 * PITCH; z += 256) Al[z] = __float2bfloat16(0.f);
        __syncthreads();
    }
#pragma unroll
    for (int c = 0; c < CS; ++c) {
        int pos = wave * (16 * CS) + c * 16 + n16;    // within-block col
        int col = colbase + c * 16 + n16;
        int oi = col / MP, lc = col - oi * MP;
        bool valid = (oi < NOUT) && (lc < MR);
        float bb = 0.f;
        if (valid) {
            const bf16* bp = (oi == 0) ? b0 : (oi == 1) ? b1 : b2;
            bb = tof(bp[lc]);
        }
        int stp;
        if (PACK) {
            int hh = lc / 47, cc2 = lc - hh * 47;
            int jj = cc2 & 15, kk2 = cc2 >> 4;
            int l = hh * 16 + jj;
            stp = (kk2 < 2) ? (2 * l + kk2) : (128 + l);
        } else {
            stp = pos;
        }
#pragma unroll
        for (int rt = 0; rt < 4; ++rt) {
#pragma unroll
            for (int i = 0; i < 4; ++i) {
                int rl = rt * 16 + quad * 4 + i;
                if (valid) Al[rl * PITCH + stp] = __float2bfloat16(acc[rt][c][i] + bb);
            }
        }
    }
    __syncthreads();
    // ---- coalesced store: 8-elem (16B) groups; PACK stage IS the split layout ----
    constexpr int NG = CS64 / 8;
    for (int t = tid; t < 64 * NG; t += 256) {
        int rl = t / NG, g = t % NG;
        int row = row0 + rl;
        if (row >= Nn) continue;
        int pos0 = g * 8;
        int oi, lc0;
        if (PACK) { oi = blockIdx.y; lc0 = pos0; }    // y-block = full oi zone
        else {
            int col0 = blockIdx.y * CS64 + pos0;      // 8-group within one oi
            oi = col0 / MP; lc0 = col0 - oi * MP;
        }
        if (oi >= NOUT) continue;
        bf16* o = (oi == 0) ? o0 : (oi == 1) ? o1 : o2;
        int4 v = *(int4*)&Al[rl * PITCH + pos0];
        *(int4*)&o[(size_t)row * OSTR + lc0] = v;
    }
}

// ---------------- fused GATv2 edge kernel, M=128 (layers 0,1) ----------------
// 256 threads = 4 dsts/block. Lane holds cols (2*lane, 2*lane+1). MAX-FREE
// softmax, log2e folded into attn. Packed-FP32 math. srcW loads are WAVE-
// UNIFORM -> s_load (near-free); NO alignment peel.
template <bool RESBN>
__global__ __launch_bounds__(256) void gat_fused_128(
    const bf16* __restrict__ fs, const bf16* __restrict__ fd,
    const unsigned* __restrict__ srcW, const int* __restrict__ ptr,
    const int* __restrict__ perm,
    const bf16* __restrict__ attn, const bf16* __restrict__ resb,
    const float* __restrict__ sums, const bf16* __restrict__ gv,
    const bf16* __restrict__ bev, bf16* __restrict__ hout) {
    const int wave = threadIdx.x >> 6, lane = threadIdx.x & 63;
    const int di = blockIdx.x * 4 + wave;
    if (di >= Nn) return;
    const int d = perm[di];
    const int c0 = lane * 2;
    const unsigned c0b = (unsigned)c0 * 2u;
    ushort2 aq = *(const ushort2*)&attn[c0];
    float a0 = b2f(aq.x) * L2E, a1 = b2f(aq.y) * L2E;
    const f32x2 Av = pk2(0.6f * a0, 0.6f * a1);
    const f32x2 Bv = pk2(0.4f * a0, 0.4f * a1);
    ushort2 dq = *(const ushort2*)&fd[(size_t)d * HD + c0];
    const f32x2 fdv = pk2(b2f(dq.x), b2f(dq.y));
    const char* fsb = (const char*)fs;
    float l = 0.f;
    f32x2 Ov = pk2(0.f, 0.f);
    int e = ptr[d];
    const int e1 = ptr[d + 1];
    for (; e + 3 < e1; e += 4) {
        unsigned vA = srcW[e] + c0b, vB = srcW[e + 1] + c0b;
        unsigned vC = srcW[e + 2] + c0b, vD = srcW[e + 3] + c0b;
        ushort2 qA = *(const ushort2*)(fsb + vA);
        ushort2 qB = *(const ushort2*)(fsb + vB);
        ushort2 qC = *(const ushort2*)(fsb + vC);
        ushort2 qD = *(const ushort2*)(fsb + vD);
        f32x2 fA = pk2(b2f(qA.x), b2f(qA.y));
        f32x2 fB = pk2(b2f(qB.x), b2f(qB.y));
        f32x2 fC = pk2(b2f(qC.x), b2f(qC.y));
        f32x2 fD = pk2(b2f(qD.x), b2f(qD.y));
        f32x2 xA = fA + fdv, xB = fB + fdv, xC = fC + fdv, xD = fD + fdv;
        f32x2 tA = pfma2(pabs2(xA), Bv, xA * Av);
        f32x2 tB = pfma2(pabs2(xB), Bv, xB * Av);
        f32x2 tC = pfma2(pabs2(xC), Bv, xC * Av);
        f32x2 tD = pfma2(pabs2(xD), Bv, xD * Av);
        float pA = tA.x + tA.y, pB = tB.x + tB.y;
        float pC = tC.x + tC.y, pD = tD.x + tD.y;
        pA = sum16(pA); pB = sum16(pB); pC = sum16(pC); pD = sum16(pD);
        float eA = __builtin_amdgcn_exp2f(pA), eB = __builtin_amdgcn_exp2f(pB);
        float eC = __builtin_amdgcn_exp2f(pC), eD = __builtin_amdgcn_exp2f(pD);
        l += (eA + eB) + (eC + eD);
        Ov = pfma2(pk2(eA, eA), fA, Ov);
        Ov = pfma2(pk2(eB, eB), fB, Ov);
        Ov = pfma2(pk2(eC, eC), fC, Ov);
        Ov = pfma2(pk2(eD, eD), fD, Ov);
    }
    for (; e < e1; ++e) {
        unsigned v = srcW[e] + c0b;
        ushort2 fq = *(const ushort2*)(fsb + v);
        f32x2 f = pk2(b2f(fq.x), b2f(fq.y));
        f32x2 x = f + fdv;
        f32x2 t = pfma2(pabs2(x), Bv, x * Av);
        float p = sum16(t.x + t.y);
        float pe = __builtin_amdgcn_exp2f(p);
        l += pe;
        Ov = pfma2(pk2(pe, pe), f, Ov);
    }
    float inv = l > 0.f ? 1.f / l : 0.f;
    ushort2 rq = *(const ushort2*)&resb[(size_t)d * HD + c0];
    float r0 = b2f(rq.x), r1 = b2f(rq.y);
    if (RESBN) {
        float mu0 = sums[c0] * (1.f / Nn), mu1 = sums[c0 + 1] * (1.f / Nn);
        float va0 = sums[HD + c0] * (1.f / Nn) - mu0 * mu0;
        float va1 = sums[HD + c0 + 1] * (1.f / Nn) - mu1 * mu1;
        float sc0 = tof(gv[c0]) * rsqrtf(va0 + EPSV);
        float sc1 = tof(gv[c0 + 1]) * rsqrtf(va1 + EPSV);
        float of0 = tof(bev[c0]) - mu0 * sc0;
        float of1 = tof(bev[c0 + 1]) - mu1 * sc1;
        r0 = fmaxf(fmaf(r0, sc0, of0), 0.f);
        r1 = fmaxf(fmaf(r1, sc1, of1), 0.f);
    }
    float v0 = fmaxf(fmaf(Ov.x, inv, r0), 0.f);  // conv activation relu
    float v1 = fmaxf(fmaf(Ov.y, inv, r1), 0.f);
    ushort2 ov; ov.x = f2u(v0); ov.y = f2u(v1);
    *(ushort2*)&hout[(size_t)d * HD + c0] = ov;
}

// ---------------- fused GATv2 edge kernel, layer 2, SPLIT-PACK stride 192 --------
// Lane l=16h+j owns cc {j, j+16} as ONE dword at byte 4l and {j+32} as ONE
// ushort at byte 256+2l (2 gathers/edge; same 384B row = same FETCH).
// Scalar fmaf chain; scalar uniform srcW (s_load); NO alignment peel.
__global__ __launch_bounds__(256) void gat_fused_188(
    const bf16* __restrict__ fs, const bf16* __restrict__ fd,
    const unsigned* __restrict__ srcW, const int* __restrict__ ptr,
    const int* __restrict__ perm,
    const bf16* __restrict__ attn, const bf16* __restrict__ rs,
    void* __restrict__ out, const int* __restrict__ flag) {
    const int wave = threadIdx.x >> 6, lane = threadIdx.x & 63;
    const int di = blockIdx.x * 4 + wave;
    if (di >= Nn) return;
    const int d = perm[di];
    const int h = lane >> 4, j = lane & 15;
    const unsigned cbA = (unsigned)lane * 4u;          // dword zone
    const unsigned cbB = 256u + (unsigned)lane * 2u;   // ushort zone
    const int ca = h * Cc + j;                         // attn is unpadded [188]
    const bool has2 = (j < 15);
    float a0 = ldb(&attn[ca]) * L2E;
    float a1 = ldb(&attn[ca + 16]) * L2E;
    float a2 = has2 ? ldb(&attn[ca + 32]) * L2E : 0.f;
    float A0 = 0.6f * a0, B0 = 0.4f * a0;
    float A1 = 0.6f * a1, B1 = 0.4f * a1;
    float A2 = 0.6f * a2, B2 = 0.4f * a2;
    const char* fdb = (const char*)fd;
    const size_t drow = (size_t)d * 384u;
    unsigned dqa = *(const unsigned*)(fdb + drow + cbA);
    unsigned short dqb = *(const unsigned short*)(fdb + drow + cbB);
    float fd0 = b2flo(dqa), fd1 = b2fhi(dqa);
    float fd2 = b2f(dqb);   // j=15: zero-filled pad, A2=B2=0 masks
    const char* fsb = (const char*)fs;
    float l = 0.f, O0 = 0.f, O1 = 0.f, O2 = 0.f;
    int e = ptr[d];
    const int e1 = ptr[d + 1];
    for (; e + 3 < e1; e += 4) {
        unsigned bA = srcW[e], bB = srcW[e + 1], bC = srcW[e + 2], bD = srcW[e + 3];
        unsigned qA = *(const unsigned*)(fsb + bA + cbA);
        unsigned qB = *(const unsigned*)(fsb + bB + cbA);
        unsigned qC = *(const unsigned*)(fsb + bC + cbA);
        unsigned qD = *(const unsigned*)(fsb + bD + cbA);
        unsigned short uA = *(const unsigned short*)(fsb + bA + cbB);
        unsigned short uB = *(const unsigned short*)(fsb + bB + cbB);
        unsigned short uC = *(const unsigned short*)(fsb + bC + cbB);
        unsigned short uD = *(const unsigned short*)(fsb + bD + cbB);
        float fA0 = b2flo(qA), fA1 = b2fhi(qA), fA2 = b2f(uA);
        float fB0 = b2flo(qB), fB1 = b2fhi(qB), fB2 = b2f(uB);
        float fC0 = b2flo(qC), fC1 = b2fhi(qC), fC2 = b2f(uC);
        float fD0 = b2flo(qD), fD1 = b2fhi(qD), fD2 = b2f(uD);
        float xA0 = fA0 + fd0, xA1 = fA1 + fd1, xA2 = fA2 + fd2;
        float xB0 = fB0 + fd0, xB1 = fB1 + fd1, xB2 = fB2 + fd2;
        float xC0 = fC0 + fd0, xC1 = fC1 + fd1, xC2 = fC2 + fd2;
        float xD0 = fD0 + fd0, xD1 = fD1 + fd1, xD2 = fD2 + fd2;
        float pA = fmaf(xA0, A0, fmaf(fabsf(xA0), B0, fmaf(xA1, A1, fmaf(fabsf(xA1), B1,
                   fmaf(xA2, A2, fabsf(xA2) * B2)))));
        float pB = fmaf(xB0, A0, fmaf(fabsf(xB0), B0, fmaf(xB1, A1, fmaf(fabsf(xB1), B1,
                   fmaf(xB2, A2, fabsf(xB2) * B2)))));
        float pC = fmaf(xC0, A0, fmaf(fabsf(xC0), B0, fmaf(xC1, A1, fmaf(fabsf(xC1), B1,
                   fmaf(xC2, A2, fabsf(xC2) * B2)))));
        float pD = fmaf(xD0, A0, fmaf(fabsf(xD0), B0, fmaf(xD1, A1, fmaf(fabsf(xD1), B1,
                   fmaf(xD2, A2, fabsf(xD2) * B2)))));
        pA = sum16(pA); pB = sum16(pB); pC = sum16(pC); pD = sum16(pD);
        float eA = __builtin_amdgcn_exp2f(pA), eB = __builtin_amdgcn_exp2f(pB);
        float eC = __builtin_amdgcn_exp2f(pC), eD = __builtin_amdgcn_exp2f(pD);
        l += (eA + eB) + (eC + eD);
        O0 = fmaf(eA, fA0, O0); O0 = fmaf(eB, fB0, O0);
        O0 = fmaf(eC, fC0, O0); O0 = fmaf(eD, fD0, O0);
        O1 = fmaf(eA, fA1, O1); O1 = fmaf(eB, fB1, O1);
        O1 = fmaf(eC, fC1, O1); O1 = fmaf(eD, fD1, O1);
        O2 = fmaf(eA, fA2, O2); O2 = fmaf(eB, fB2, O2);
        O2 = fmaf(eC, fC2, O2); O2 = fmaf(eD, fD2, O2);
    }
    for (; e < e1; ++e) {
        unsigned b = srcW[e];
        unsigned q = *(const unsigned*)(fsb + b + cbA);
        unsigned short u = *(const unsigned short*)(fsb + b + cbB);
        float f0 = b2flo(q), f1 = b2fhi(q), f2 = b2f(u);
        float x0 = f0 + fd0, x1 = f1 + fd1, x2 = f2 + fd2;
        float p = fmaf(x0, A0, fmaf(fabsf(x0), B0, fmaf(x1, A1, fmaf(fabsf(x1), B1,
                  fmaf(x2, A2, fabsf(x2) * B2)))));
        p = sum16(p);
        float pe = __builtin_amdgcn_exp2f(p);
        l += pe;
        O0 = fmaf(pe, f0, O0);
        O1 = fmaf(pe, f1, O1);
        O2 = fmaf(pe, f2, O2);
    }
    // epilogue: +res, head-mean across lane groups, log_softmax, store
    float inv = l > 0.f ? 1.f / l : 0.f;
    const char* rb_ = (const char*)rs;
    unsigned rqa = *(const unsigned*)(rb_ + drow + cbA);
    unsigned short rqb = *(const unsigned short*)(rb_ + drow + cbB);
    float v0 = fmaf(O0, inv, b2flo(rqa));
    float v1 = fmaf(O1, inv, b2fhi(rqa));
    float v2 = has2 ? fmaf(O2, inv, b2f(rqb)) : 0.f;
    v0 += __shfl_xor(v0, 16); v0 += __shfl_xor(v0, 32); v0 *= 0.25f;
    v1 += __shfl_xor(v1, 16); v1 += __shfl_xor(v1, 32); v1 *= 0.25f;
    v2 += __shfl_xor(v2, 16); v2 += __shfl_xor(v2, 32); v2 *= 0.25f;
    float mx = fmaxf(v0, v1);
    if (has2) mx = fmaxf(mx, v2);
    mx = max16(mx);
    float sm = __expf(v0 - mx) + __expf(v1 - mx) + (has2 ? __expf(v2 - mx) : 0.f);
    sm = sum16(sm);
    if (h == 0) {
        float ls = mx + __log2f(sm) * LN2;
        if (*flag) {
            bf16* o = (bf16*)out + (size_t)d * Cc;
            o[j] = __float2bfloat16(v0 - ls);
            o[j + 16] = __float2bfloat16(v1 - ls);
            if (has2) o[j + 32] = __float2bfloat16(v2 - ls);
        } else {
            float* o = (float*)out + (size_t)d * Cc;
            o[j] = v0 - ls;
            o[j + 16] = v1 - ls;
            if (has2) o[j + 32] = v2 - ls;
        }
    }
}

// ---------------- per-column BN stats over bf16 h (atomic combine) ----------------
// 391 blocks x 64 threads (ONE wave); thread c owns col pair (2c,2c+1) via
// ushort2 loads -> 64 lanes x 4B = full 256B-row coalescing. Indices stay
// within sums[0..255]. ONE atomicAdd per thread per stat.
__global__ void col_stats(const bf16* __restrict__ in, float* __restrict__ sums) {
    int c = threadIdx.x;  // 64 threads -> cols (2c, 2c+1), 2c in [0,126]
    int r0 = blockIdx.x * 256;
    int r1 = r0 + 256; if (r1 > Nn) r1 = Nn;
    float s0 = 0.f, s1 = 0.f, q0 = 0.f, q1 = 0.f;
    for (int r = r0; r < r1; ++r) {
        ushort2 v = *(const ushort2*)&in[(size_t)r * HD + 2 * c];
        float a = b2f(v.x), b = b2f(v.y);
        s0 += a; q0 = fmaf(a, a, q0);
        s1 += b; q1 = fmaf(b, b, q1);
    }
    atomicAdd(&sums[2 * c], s0);
    atomicAdd(&sums[2 * c + 1], s1);
    atomicAdd(&sums[HD + 2 * c], q0);
    atomicAdd(&sums[HD + 2 * c + 1], q1);
}

extern "C" void kernel_launch(void* const* d_in, const int* in_sizes, int n_in,
                              void* d_out, int out_size, void* d_ws, size_t ws_size,
                              hipStream_t stream) {
    (void)in_sizes; (void)n_in; (void)out_size; (void)ws_size;
    const void* x = d_in[0];
    const int* src = (const int*)d_in[1];
    const int* dst = (const int*)d_in[2];

    char* ws = (char*)d_ws;
    size_t off = 0;
    auto alloc = [&](size_t bytes) {
        void* p = ws + off;
        off += (bytes + 255) & ~(size_t)255;
        return p;
    };
    // rs (38.4 MB, [Nn][192]) aliases xb+rb (51.2 MB): both dead before L2 GEMM.
    bf16* xb = (bf16*)alloc((size_t)Nn * 128 * 2);    // 25.6 MB (stride-128 padded x)
    bf16* rb = (bf16*)alloc((size_t)Nn * HD * 2);     // 25.6 MB
    bf16* rs = xb;                                    // [Nn][HCP] alias
    bf16* fs = (bf16*)alloc((size_t)Nn * HCP * 2);    // 38.4 MB
    bf16* fd = (bf16*)alloc((size_t)Nn * HCP * 2);    // 38.4 MB
    bf16* hbA = (bf16*)alloc((size_t)Nn * HD * 2);    // 25.6 MB
    bf16* hbB = (bf16*)alloc((size_t)Nn * HD * 2);    // 25.6 MB
    int* ptr = (int*)alloc((Nn + 1) * 4);             // 400 KB
    bf16* wtb = (bf16*)alloc((size_t)WROWS * 128 * 2);// 328 KB
    float* bns0 = (float*)alloc(2 * HD * 4);
    float* bns1 = (float*)alloc(2 * HD * 4);
    bf16* pb = (bf16*)alloc(4096 * 2);
    int* flag = (int*)alloc(256);
    unsigned* w384 = (unsigned*)alloc((size_t)Ee * 4);// 4 MB
    unsigned* w256 = (unsigned*)alloc((size_t)Ee * 4);// 4 MB
    int* cnt = (int*)alloc((size_t)256 * NBLK * 4);   // 400 KB
    int* cbase = (int*)alloc((size_t)256 * NBLK * 4); // 400 KB
    int* totals = (int*)alloc(256 * 4);
    int* perm = (int*)alloc((size_t)Nn * 4);          // 400 KB

    // ---- small-param conversion (biases/attn/bn): d_in idx -> pb arena ----
    static const int spIdx[NSP] = {4, 6, 7, 9, 11, 13, 14, 16, 18, 19, 21, 22, 23, 24, 25};
    static const int spSz[NSP]  = {HD, HD, HD, HD, HD, HD, HD, HC, HC, HC, HC, HD, HD, HD, HD};
    CvtTab tab;
    int tot = 0;
    for (int i = 0; i < NSP; ++i) { tab.src[i] = d_in[spIdx[i]]; tab.off[i] = tot; tot += spSz[i]; }
    tab.off[NSP] = tot;
    const bf16 *bsrc0 = pb + tab.off[0], *bdst0 = pb + tab.off[1], *attn0 = pb + tab.off[2],
               *bres0 = pb + tab.off[3], *bsrc1 = pb + tab.off[4], *bdst1 = pb + tab.off[5],
               *attn1 = pb + tab.off[6], *bsrc2 = pb + tab.off[7], *bdst2 = pb + tab.off[8],
               *attn2 = pb + tab.off[9], *bres2 = pb + tab.off[10],
               *g0 = pb + tab.off[11], *be0 = pb + tab.off[12],
               *g1 = pb + tab.off[13], *be1 = pb + tab.off[14];

    // ---- packed Wt: rows [0,384)=L0, [384,640)=L1, [640,1216)=L2 @MP=192, pad->1280 ----
    PrepTab pt;
    static const int wIdx[8] = {3, 5, 8, 10, 12, 15, 17, 20};
    static const int wK[8]   = {INF_, INF_, INF_, HD, HD, HD, HD, HD};
    static const int wM[8]   = {HD, HD, HD, HD, HD, HC, HC, HC};
    static const int wMP[8]  = {128, 128, 128, 128, 128, 192, 192, 192};
    static const int wR0[8]  = {0, 128, 256, 384, 512, 640, 832, 1024};
    for (int i = 0; i < 8; ++i) {
        pt.src[i] = d_in[wIdx[i]]; pt.row0[i] = wR0[i];
        pt.K[i] = wK[i]; pt.M[i] = wM[i]; pt.MP[i] = wMP[i];
    }

    // ---- mega prepare (detect + cvt_x + weights + params + src offsets + ptr/hist) --
    const int prepGrid = (Nn * 128 + 255) / 256;   // 50000 blocks, covers all jobs
    prepare<<<prepGrid, 256, 0, stream>>>(x, src, dst, pt, tab, tot,
                                          xb, wtb, pb, w384, w256, ptr, cnt,
                                          bns0, bns1, flag);
    deg_totals<<<64, 256, 0, stream>>>(cnt, totals);
    deg_bases<<<64, 256, 0, stream>>>(cnt, totals, cbase);
    deg_scatter_blk<<<NBLK, 256, 0, stream>>>(ptr, cbase, perm);

    const int fusedGrid = (Nn + 3) / 4;   // 256-thread blocks, 4 dsts each
    const int statsGrid = NBLK;
    const int rowBlk = (Nn + 63) / 64;  // 1563

    // ---------------- layer 0 (384 cols: y=2 x CS=3) ----------------
    gemm_big<128, 3, 3, false, false, HD><<<dim3(rowBlk, 2), 256, 0, stream>>>(
        xb, wtb, bsrc0, bdst0, bres0, fs, fd, rb, HD, nullptr, nullptr, nullptr);
    gat_fused_128<false><<<fusedGrid, 256, 0, stream>>>(fs, fd, w256, ptr, perm,
                                                        attn0, rb, nullptr, nullptr,
                                                        nullptr, hbA);
    col_stats<<<statsGrid, 64, 0, stream>>>(hbA, bns0);

    // ---------------- layer 1 (256 cols: y=2 x CS=2) ----------------
    gemm_big<128, 2, 2, true, false, HD><<<dim3(rowBlk, 2), 256, 0, stream>>>(
        hbA, wtb + (size_t)384 * 128, bsrc1, bdst1, nullptr, fs, fd, nullptr, HD,
        bns0, g0, be0);
    gat_fused_128<true><<<fusedGrid, 256, 0, stream>>>(fs, fd, w256, ptr, perm,
                                                       attn1, hbA, bns0, g0, be0, hbB);
    col_stats<<<statsGrid, 64, 0, stream>>>(hbB, bns1);

    // ---------------- layer 2 (576 cols: y=3 x CS=3, split-pack coalesced outputs) --
    gemm_big<192, 3, 3, true, true, HCP><<<dim3(rowBlk, 3), 256, 0, stream>>>(
        hbB, wtb + (size_t)640 * 128, bsrc2, bdst2, bres2, fs, fd, rs, HC,
        bns1, g1, be1);
    gat_fused_188<<<fusedGrid, 256, 0, stream>>>(fs, fd, w384, ptr, perm, attn2, rs,
                                                 d_out, flag);
}

// Round 15
// 626.727 us; speedup vs baseline: 1.3305x; 1.0378x over previous
//
#include <hip/hip_runtime.h>
#include <hip/hip_bf16.h>

#define Nn 100000
#define Ee 1000000
#define INF_ 100
#define Hh 4
#define Dd 32
#define HD 128
#define Cc 47
#define HC 188
#define HCP 192
#define EPSV 1e-5f
#define SLOPE 0.2f
#define NBLK ((Nn + 255) / 256)

typedef __hip_bfloat16 bf16;
typedef __attribute__((ext_vector_type(8))) short short8;
typedef __attribute__((ext_vector_type(4))) float f32x4;
typedef __attribute__((ext_vector_type(2))) float f32x2;

__device__ __forceinline__ float tof(bf16 v) { return __bfloat162float(v); }
__device__ __forceinline__ float b2f(unsigned short u) {
    return __uint_as_float((unsigned)u << 16);
}
__device__ __forceinline__ float b2flo(unsigned u) {
    return __uint_as_float(u << 16);
}
__device__ __forceinline__ float b2fhi(unsigned u) {
    return __uint_as_float(u & 0xFFFF0000u);
}
__device__ __forceinline__ float ldb(const bf16* p) {
    return b2f(*(const unsigned short*)p);
}
__device__ __forceinline__ unsigned short f2u(float v) {
    bf16 t = __float2bfloat16(v);
    return *(unsigned short*)&t;
}
__device__ __forceinline__ f32x2 pk2(float x, float y) {
    f32x2 r; r.x = x; r.y = y; return r;
}
__device__ __forceinline__ f32x2 pabs2(f32x2 v) {          // v_pk_max_f32 v, -v
    return __builtin_elementwise_max(v, -v);
}
__device__ __forceinline__ f32x2 pfma2(f32x2 a, f32x2 b, f32x2 c) {
    return __builtin_elementwise_fma(a, b, c);             // v_pk_fma_f32
}

// DPP-fused 16-lane reduces (quad_perm swaps + row rotates; row=16 lanes).
template <int C>
__device__ __forceinline__ float dppadd(float v) {
    int m = __builtin_amdgcn_update_dpp(0, __float_as_int(v), C, 0xF, 0xF, false);
    return v + __int_as_float(m);
}
template <int C>
__device__ __forceinline__ float dppmax(float v) {
    int m = __builtin_amdgcn_update_dpp(0, __float_as_int(v), C, 0xF, 0xF, false);
    return fmaxf(v, __int_as_float(m));
}
__device__ __forceinline__ float sum16(float p) {
    p = dppadd<0xB1>(p);   // quad_perm [1,0,3,2]
    p = dppadd<0x4E>(p);   // quad_perm [2,3,0,1]
    p = dppadd<0x124>(p);  // row_ror:4
    p = dppadd<0x128>(p);  // row_ror:8
    return p;
}
__device__ __forceinline__ float max16(float p) {
    p = dppmax<0xB1>(p); p = dppmax<0x4E>(p);
    p = dppmax<0x124>(p); p = dppmax<0x128>(p);
    return p;
}

#define L2E 1.4426950408889634f
#define LN2 0.6931471805599453f

__device__ __forceinline__ float ld_any(const void* p, int i, int isbf) {
    return isbf ? tof(((const bf16*)p)[i]) : ((const float*)p)[i];
}

__device__ __forceinline__ int lbound(const int* __restrict__ dst, int n) {
    int lo = 0, hi = Ee;
    while (lo < hi) {
        int mid = (lo + hi) >> 1;
        if (dst[mid] < n) lo = mid + 1; else hi = mid;
    }
    return lo;
}

// ---------------- MEGA prepare kernel ----------------
// Each block independently derives the dtype flag (ballot over x[0..255] words,
// L2-hot, deterministic) -> no cross-kernel flag dependency. Jobs partitioned
// by global index: cvt_x | weight pack | small params | src byte-offsets |
// bns zeroing | CSR ptr + BLOCK-LOCAL degree histogram (lower_bounds shared
// through LDS so hist needs no globally-complete ptr).
#define WROWS 1280
#define NSP 15
struct PrepTab { const void* src[8]; int row0[8]; int K[8]; int M[8]; int MP[8]; };
struct CvtTab { const void* src[NSP]; int off[NSP + 1]; };

__global__ __launch_bounds__(256) void prepare(
    const void* __restrict__ x, const int* __restrict__ src,
    const int* __restrict__ dst,
    PrepTab pt, CvtTab ct, int tot,
    bf16* __restrict__ xb, bf16* __restrict__ wtb, bf16* __restrict__ pb,
    unsigned* __restrict__ w384, unsigned* __restrict__ w256,
    int* __restrict__ ptr, int* __restrict__ cnt,
    float* __restrict__ z0, float* __restrict__ z1, int* __restrict__ flag) {
    __shared__ int wc[4];
    __shared__ int lbv[257];
    __shared__ int lh[256];
    const int t = threadIdx.x;
    // ---- per-block dtype detect ----
    unsigned w = ((const unsigned*)x)[t];
    float dv = __uint_as_float((w & 0xFFFFu) << 16);
    float da = fabsf(dv);
    unsigned long long m = __ballot(da > 1e-4f && da < 10.f);
    if ((t & 63) == 0) wc[t >> 6] = __popcll(m);
    __syncthreads();
    const int isbf = (wc[0] + wc[1] + wc[2] + wc[3]) >= 128;
    if (blockIdx.x == 0 && t == 0) *flag = isbf;

    const int gi = blockIdx.x * 256 + t;
    // ---- cvt_x: [Nn][100] -> bf16 [Nn][128] ----
    if (gi < Nn * 128) {
        int row = gi >> 7, col = gi & 127;
        float v = (col < INF_) ? ld_any(x, row * INF_ + col, isbf) : 0.f;
        xb[gi] = __float2bfloat16(v);
    }
    // ---- weights -> packed transposed Wt[1280][128] ----
    if (gi < WROWS * 128) {
        int row = gi >> 7, k = gi & 127;
        float v = 0.f;
#pragma unroll
        for (int q = 0; q < 8; ++q) {
            if (row >= pt.row0[q] && row < pt.row0[q] + pt.MP[q]) {
                int mm = row - pt.row0[q];
                if (mm < pt.M[q] && k < pt.K[q])
                    v = ld_any(pt.src[q], k * pt.M[q] + mm, isbf);
            }
        }
        wtb[gi] = __float2bfloat16(v);
    }
    // ---- small params ----
    if (gi < tot) {
        int seg = 0;
        while (gi >= ct.off[seg + 1]) seg++;
        pb[gi] = __float2bfloat16(ld_any(ct.src[seg], gi - ct.off[seg], isbf));
    }
    // ---- pre-scaled src byte offsets ----
    if (gi < Ee) {
        unsigned s = (unsigned)src[gi];
        w384[gi] = s * 384u;  // stride HCP*2 bytes (layer-2 split-pack fs)
        w256[gi] = s << 8;    // stride HD*2 bytes  (layer-0/1 fs)
    }
    // ---- BN accumulator zeroing ----
    if (gi < 2 * HD) { z0[gi] = 0.f; z1[gi] = 0.f; }
    // ---- CSR ptr + block-local degree histogram ----
    if (blockIdx.x < NBLK) {
        int nn = gi;
        int lb = Ee;
        if (nn <= Nn) { lb = lbound(dst, nn); ptr[nn] = lb; }
        lbv[t] = lb;
        if (t == 255) lbv[256] = (nn + 1 <= Nn) ? lbound(dst, nn + 1) : Ee;
        lh[t] = 0;
        __syncthreads();
        if (nn < Nn) {
            int dg = lbv[t + 1] - lbv[t]; if (dg > 255) dg = 255;
            atomicAdd(&lh[dg], 1);
        }
        __syncthreads();
        cnt[t * NBLK + blockIdx.x] = lh[t];
    }
}

// ---------------- degree-descending LPT permutation -------------------------------
// TWO kernels, deliberately: fusing the suffix-total into deg_bases made each
// wave run ~1800 serially-dependent loads at 1.6% occupancy (204us, r13).
// deg_totals spreads that work over 256 parallel waves (~6 coalesced loads each).
__global__ void deg_totals(const int* __restrict__ cnt, int* __restrict__ totals) {
    int wave = threadIdx.x >> 6, lane = threadIdx.x & 63;
    int bin = blockIdx.x * 4 + wave;
    int s = 0;
    for (int k = lane; k < NBLK; k += 64) s += cnt[bin * NBLK + k];
#pragma unroll
    for (int o = 1; o < 64; o <<= 1) s += __shfl_xor(s, o);
    if (lane == 0) totals[bin] = s;
}

// one wave per bin: binbase = sum of totals over HIGHER-degree bins (256 tiny
// loads, L2-hot), then chunked 64-lane exclusive prefix over per-block counts.
__global__ void deg_bases(const int* __restrict__ cnt, const int* __restrict__ totals,
                          int* __restrict__ base) {
    int wave = threadIdx.x >> 6, lane = threadIdx.x & 63;
    int bin = blockIdx.x * 4 + wave;
    int bb = 0;
    for (int b = bin + 1 + lane; b < 256; b += 64) bb += totals[b];
#pragma unroll
    for (int o = 1; o < 64; o <<= 1) bb += __shfl_xor(bb, o);
    int run = bb;   // descending-degree base for this bin
    for (int k0 = 0; k0 < NBLK; k0 += 64) {
        int k = k0 + lane;
        int c = (k < NBLK) ? cnt[bin * NBLK + k] : 0;
        int p = c;
#pragma unroll
        for (int o = 1; o < 64; o <<= 1) {
            int t = __shfl_up(p, o);
            if (lane >= o) p += t;
        }
        if (k < NBLK) base[bin * NBLK + k] = run + (p - c);
        run += __shfl(p, 63);
    }
}

__global__ void deg_scatter_blk(const int* __restrict__ ptr, const int* __restrict__ base,
                                int* __restrict__ perm) {
    __shared__ int lh[256];
    int t = threadIdx.x;
    lh[t] = 0;
    __syncthreads();
    int n = blockIdx.x * 256 + t;
    if (n < Nn) {
        int dg = ptr[n + 1] - ptr[n]; if (dg > 255) dg = 255;
        int loc = atomicAdd(&lh[dg], 1);   // LDS atomic: one CU, cheap
        perm[base[dg * NBLK + blockIdx.x] + loc] = n;
    }
}

// ---------------- big-tile MFMA GEMM: 64 rows x (64*CS) cols per block -------------
// y-grid column split (deep grid hides store latency; NY-in-kernel regressed).
// LDS-staged COALESCED epilogue. PACK (layer-2 SPLIT layout): col lc -> h=lc/47,
// cc=lc%47, j=cc&15, k=cc>>4, lane l=16h+j; k<2 -> elem 2l+k (dword zone,
// bytes 0..255); k=2 -> elem 128+l (ushort zone, bytes 256..383). 384B row,
// zero traffic overhead; gat_188 needs only 2 gathers/edge.
template <int MP, int NOUT, int CS, bool ABN, bool PACK, int OSTR>
__global__ __launch_bounds__(256, 4) void gemm_big(
    const bf16* __restrict__ A, const bf16* __restrict__ Wt,
    const bf16* __restrict__ b0, const bf16* __restrict__ b1,
    const bf16* __restrict__ b2,
    bf16* __restrict__ o0, bf16* __restrict__ o1, bf16* __restrict__ o2,
    int MR, const float* __restrict__ sums,
    const bf16* __restrict__ gg, const bf16* __restrict__ bbn) {
    constexpr int CS64 = CS * 64;
    constexpr int PITCH = CS64 + 8;                 // 16B-aligned row stride
    constexpr int LSZ = (64 * PITCH > 64 * 136) ? 64 * PITCH : 64 * 136;
    __shared__ __align__(16) bf16 Al[LSZ];
    __shared__ float scb[ABN ? HD : 1], ofb[ABN ? HD : 1];
    const int row0 = blockIdx.x * 64;
    const int tid = threadIdx.x;
    if (ABN) {
        if (tid < HD) {
            float mu = sums[tid] * (1.f / Nn);
            float var = sums[HD + tid] * (1.f / Nn) - mu * mu;
            float sc = tof(gg[tid]) * rsqrtf(var + EPSV);
            scb[tid] = sc;
            ofb[tid] = tof(bbn[tid]) - mu * sc;
        }
        __syncthreads();
    }
#pragma unroll
    for (int j = 0; j < 4; ++j) {
        int idx = tid + j * 256;          // 0..1023 int4 slots
        int r = idx >> 4, kk = (idx & 15) * 8;
        int4 val = {0, 0, 0, 0};
        if (row0 + r < Nn) {
            val = *(const int4*)&A[(size_t)(row0 + r) * 128 + kk];
            if (ABN) {
                short8 av = *(short8*)&val;
                bf16 tmp[8];
#pragma unroll
                for (int u = 0; u < 8; ++u) {
                    float v = b2f((unsigned short)av[u]);
                    v = fmaxf(fmaf(v, scb[kk + u], ofb[kk + u]), 0.f);
                    tmp[u] = __float2bfloat16(v);
                }
                val = *(int4*)tmp;
            }
        }
        *(int4*)&Al[r * 136 + kk] = val;
    }
    __syncthreads();
    const int wave = tid >> 6, lane = tid & 63;
    const int n16 = lane & 15, quad = lane >> 4;
    const int colbase = blockIdx.y * CS64 + wave * (16 * CS);
    f32x4 acc[4][CS];
#pragma unroll
    for (int rt = 0; rt < 4; ++rt)
#pragma unroll
        for (int c = 0; c < CS; ++c) acc[rt][c] = (f32x4){0.f, 0.f, 0.f, 0.f};
    const bf16* wb[CS];
#pragma unroll
    for (int c = 0; c < CS; ++c)
        wb[c] = Wt + (size_t)(colbase + c * 16 + n16) * 128 + quad * 8;
    const bf16* ap = Al + n16 * 136 + quad * 8;
#pragma unroll
    for (int ks = 0; ks < 4; ++ks) {
        short8 bf[CS];
#pragma unroll
        for (int c = 0; c < CS; ++c) bf[c] = *(const short8*)(wb[c] + ks * 32);
#pragma unroll
        for (int rt = 0; rt < 4; ++rt) {
            short8 af = *(const short8*)(ap + rt * 16 * 136 + ks * 32);
#pragma unroll
            for (int c = 0; c < CS; ++c)
                acc[rt][c] = __builtin_amdgcn_mfma_f32_16x16x32_bf16(af, bf[c], acc[rt][c], 0, 0, 0);
        }
    }
    // ---- stage epilogue: Al reads done, reuse as [64][PITCH] ----
    __syncthreads();
    if (PACK) {   // zero pad slots (ushort-zone j=15 lanes + pitch cols)
        for (int z = tid; z < 64 * PITCH; z += 256) Al[z] = __float2bfloat16(0.f);
        __syncthreads();
    }
#pragma unroll
    for (int c = 0; c < CS; ++c) {
        int pos = wave * (16 * CS) + c * 16 + n16;    // within-block col
        int col = colbase + c * 16 + n16;
        int oi = col / MP, lc = col - oi * MP;
        bool valid = (oi < NOUT) && (lc < MR);
        float bb = 0.f;
        if (valid) {
            const bf16* bp = (oi == 0) ? b0 : (oi == 1) ? b1 : b2;
            bb = tof(bp[lc]);
        }
        int stp;
        if (PACK) {
            int hh = lc / 47, cc2 = lc - hh * 47;
            int jj = cc2 & 15, kk2 = cc2 >> 4;
            int l = hh * 16 + jj;
            stp = (kk2 < 2) ? (2 * l + kk2) : (128 + l);
        } else {
            stp = pos;
        }
#pragma unroll
        for (int rt = 0; rt < 4; ++rt) {
#pragma unroll
            for (int i = 0; i < 4; ++i) {
                int rl = rt * 16 + quad * 4 + i;
                if (valid) Al[rl * PITCH + stp] = __float2bfloat16(acc[rt][c][i] + bb);
            }
        }
    }
    __syncthreads();
    // ---- coalesced store: 8-elem (16B) groups; PACK stage IS the split layout ----
    constexpr int NG = CS64 / 8;
    for (int t = tid; t < 64 * NG; t += 256) {
        int rl = t / NG, g = t % NG;
        int row = row0 + rl;
        if (row >= Nn) continue;
        int pos0 = g * 8;
        int oi, lc0;
        if (PACK) { oi = blockIdx.y; lc0 = pos0; }    // y-block = full oi zone
        else {
            int col0 = blockIdx.y * CS64 + pos0;      // 8-group within one oi
            oi = col0 / MP; lc0 = col0 - oi * MP;
        }
        if (oi >= NOUT) continue;
        bf16* o = (oi == 0) ? o0 : (oi == 1) ? o1 : o2;
        int4 v = *(int4*)&Al[rl * PITCH + pos0];
        *(int4*)&o[(size_t)row * OSTR + lc0] = v;
    }
}

// ---------------- fused GATv2 edge kernel, M=128 (layers 0,1) ----------------
// 256 threads = 4 dsts/block. Lane holds cols (2*lane, 2*lane+1). MAX-FREE
// softmax, log2e folded into attn. Packed-FP32 math. srcW loads are WAVE-
// UNIFORM -> s_load (near-free); NO alignment peel.
template <bool RESBN>
__global__ __launch_bounds__(256) void gat_fused_128(
    const bf16* __restrict__ fs, const bf16* __restrict__ fd,
    const unsigned* __restrict__ srcW, const int* __restrict__ ptr,
    const int* __restrict__ perm,
    const bf16* __restrict__ attn, const bf16* __restrict__ resb,
    const float* __restrict__ sums, const bf16* __restrict__ gv,
    const bf16* __restrict__ bev, bf16* __restrict__ hout) {
    const int wave = threadIdx.x >> 6, lane = threadIdx.x & 63;
    const int di = blockIdx.x * 4 + wave;
    if (di >= Nn) return;
    const int d = perm[di];
    const int c0 = lane * 2;
    const unsigned c0b = (unsigned)c0 * 2u;
    ushort2 aq = *(const ushort2*)&attn[c0];
    float a0 = b2f(aq.x) * L2E, a1 = b2f(aq.y) * L2E;
    const f32x2 Av = pk2(0.6f * a0, 0.6f * a1);
    const f32x2 Bv = pk2(0.4f * a0, 0.4f * a1);
    ushort2 dq = *(const ushort2*)&fd[(size_t)d * HD + c0];
    const f32x2 fdv = pk2(b2f(dq.x), b2f(dq.y));
    const char* fsb = (const char*)fs;
    float l = 0.f;
    f32x2 Ov = pk2(0.f, 0.f);
    int e = ptr[d];
    const int e1 = ptr[d + 1];
    for (; e + 3 < e1; e += 4) {
        unsigned vA = srcW[e] + c0b, vB = srcW[e + 1] + c0b;
        unsigned vC = srcW[e + 2] + c0b, vD = srcW[e + 3] + c0b;
        ushort2 qA = *(const ushort2*)(fsb + vA);
        ushort2 qB = *(const ushort2*)(fsb + vB);
        ushort2 qC = *(const ushort2*)(fsb + vC);
        ushort2 qD = *(const ushort2*)(fsb + vD);
        f32x2 fA = pk2(b2f(qA.x), b2f(qA.y));
        f32x2 fB = pk2(b2f(qB.x), b2f(qB.y));
        f32x2 fC = pk2(b2f(qC.x), b2f(qC.y));
        f32x2 fD = pk2(b2f(qD.x), b2f(qD.y));
        f32x2 xA = fA + fdv, xB = fB + fdv, xC = fC + fdv, xD = fD + fdv;
        f32x2 tA = pfma2(pabs2(xA), Bv, xA * Av);
        f32x2 tB = pfma2(pabs2(xB), Bv, xB * Av);
        f32x2 tC = pfma2(pabs2(xC), Bv, xC * Av);
        f32x2 tD = pfma2(pabs2(xD), Bv, xD * Av);
        float pA = tA.x + tA.y, pB = tB.x + tB.y;
        float pC = tC.x + tC.y, pD = tD.x + tD.y;
        pA = sum16(pA); pB = sum16(pB); pC = sum16(pC); pD = sum16(pD);
        float eA = __builtin_amdgcn_exp2f(pA), eB = __builtin_amdgcn_exp2f(pB);
        float eC = __builtin_amdgcn_exp2f(pC), eD = __builtin_amdgcn_exp2f(pD);
        l += (eA + eB) + (eC + eD);
        Ov = pfma2(pk2(eA, eA), fA, Ov);
        Ov = pfma2(pk2(eB, eB), fB, Ov);
        Ov = pfma2(pk2(eC, eC), fC, Ov);
        Ov = pfma2(pk2(eD, eD), fD, Ov);
    }
    for (; e < e1; ++e) {
        unsigned v = srcW[e] + c0b;
        ushort2 fq = *(const ushort2*)(fsb + v);
        f32x2 f = pk2(b2f(fq.x), b2f(fq.y));
        f32x2 x = f + fdv;
        f32x2 t = pfma2(pabs2(x), Bv, x * Av);
        float p = sum16(t.x + t.y);
        float pe = __builtin_amdgcn_exp2f(p);
        l += pe;
        Ov = pfma2(pk2(pe, pe), f, Ov);
    }
    float inv = l > 0.f ? 1.f / l : 0.f;
    ushort2 rq = *(const ushort2*)&resb[(size_t)d * HD + c0];
    float r0 = b2f(rq.x), r1 = b2f(rq.y);
    if (RESBN) {
        float mu0 = sums[c0] * (1.f / Nn), mu1 = sums[c0 + 1] * (1.f / Nn);
        float va0 = sums[HD + c0] * (1.f / Nn) - mu0 * mu0;
        float va1 = sums[HD + c0 + 1] * (1.f / Nn) - mu1 * mu1;
        float sc0 = tof(gv[c0]) * rsqrtf(va0 + EPSV);
        float sc1 = tof(gv[c0 + 1]) * rsqrtf(va1 + EPSV);
        float of0 = tof(bev[c0]) - mu0 * sc0;
        float of1 = tof(bev[c0 + 1]) - mu1 * sc1;
        r0 = fmaxf(fmaf(r0, sc0, of0), 0.f);
        r1 = fmaxf(fmaf(r1, sc1, of1), 0.f);
    }
    float v0 = fmaxf(fmaf(Ov.x, inv, r0), 0.f);  // conv activation relu
    float v1 = fmaxf(fmaf(Ov.y, inv, r1), 0.f);
    ushort2 ov; ov.x = f2u(v0); ov.y = f2u(v1);
    *(ushort2*)&hout[(size_t)d * HD + c0] = ov;
}

// ---------------- fused GATv2 edge kernel, layer 2, SPLIT-PACK stride 192 --------
// Lane l=16h+j owns cc {j, j+16} as ONE dword at byte 4l and {j+32} as ONE
// ushort at byte 256+2l (2 gathers/edge; same 384B row = same FETCH).
// Scalar fmaf chain; scalar uniform srcW (s_load); NO alignment peel.
__global__ __launch_bounds__(256) void gat_fused_188(
    const bf16* __restrict__ fs, const bf16* __restrict__ fd,
    const unsigned* __restrict__ srcW, const int* __restrict__ ptr,
    const int* __restrict__ perm,
    const bf16* __restrict__ attn, const bf16* __restrict__ rs,
    void* __restrict__ out, const int* __restrict__ flag) {
    const int wave = threadIdx.x >> 6, lane = threadIdx.x & 63;
    const int di = blockIdx.x * 4 + wave;
    if (di >= Nn) return;
    const int d = perm[di];
    const int h = lane >> 4, j = lane & 15;
    const unsigned cbA = (unsigned)lane * 4u;          // dword zone
    const unsigned cbB = 256u + (unsigned)lane * 2u;   // ushort zone
    const int ca = h * Cc + j;                         // attn is unpadded [188]
    const bool has2 = (j < 15);
    float a0 = ldb(&attn[ca]) * L2E;
    float a1 = ldb(&attn[ca + 16]) * L2E;
    float a2 = has2 ? ldb(&attn[ca + 32]) * L2E : 0.f;
    float A0 = 0.6f * a0, B0 = 0.4f * a0;
    float A1 = 0.6f * a1, B1 = 0.4f * a1;
    float A2 = 0.6f * a2, B2 = 0.4f * a2;
    const char* fdb = (const char*)fd;
    const size_t drow = (size_t)d * 384u;
    unsigned dqa = *(const unsigned*)(fdb + drow + cbA);
    unsigned short dqb = *(const unsigned short*)(fdb + drow + cbB);
    float fd0 = b2flo(dqa), fd1 = b2fhi(dqa);
    float fd2 = b2f(dqb);   // j=15: zero-filled pad, A2=B2=0 masks
    const char* fsb = (const char*)fs;
    float l = 0.f, O0 = 0.f, O1 = 0.f, O2 = 0.f;
    int e = ptr[d];
    const int e1 = ptr[d + 1];
    for (; e + 3 < e1; e += 4) {
        unsigned bA = srcW[e], bB = srcW[e + 1], bC = srcW[e + 2], bD = srcW[e + 3];
        unsigned qA = *(const unsigned*)(fsb + bA + cbA);
        unsigned qB = *(const unsigned*)(fsb + bB + cbA);
        unsigned qC = *(const unsigned*)(fsb + bC + cbA);
        unsigned qD = *(const unsigned*)(fsb + bD + cbA);
        unsigned short uA = *(const unsigned short*)(fsb + bA + cbB);
        unsigned short uB = *(const unsigned short*)(fsb + bB + cbB);
        unsigned short uC = *(const unsigned short*)(fsb + bC + cbB);
        unsigned short uD = *(const unsigned short*)(fsb + bD + cbB);
        float fA0 = b2flo(qA), fA1 = b2fhi(qA), fA2 = b2f(uA);
        float fB0 = b2flo(qB), fB1 = b2fhi(qB), fB2 = b2f(uB);
        float fC0 = b2flo(qC), fC1 = b2fhi(qC), fC2 = b2f(uC);
        float fD0 = b2flo(qD), fD1 = b2fhi(qD), fD2 = b2f(uD);
        float xA0 = fA0 + fd0, xA1 = fA1 + fd1, xA2 = fA2 + fd2;
        float xB0 = fB0 + fd0, xB1 = fB1 + fd1, xB2 = fB2 + fd2;
        float xC0 = fC0 + fd0, xC1 = fC1 + fd1, xC2 = fC2 + fd2;
        float xD0 = fD0 + fd0, xD1 = fD1 + fd1, xD2 = fD2 + fd2;
        float pA = fmaf(xA0, A0, fmaf(fabsf(xA0), B0, fmaf(xA1, A1, fmaf(fabsf(xA1), B1,
                   fmaf(xA2, A2, fabsf(xA2) * B2)))));
        float pB = fmaf(xB0, A0, fmaf(fabsf(xB0), B0, fmaf(xB1, A1, fmaf(fabsf(xB1), B1,
                   fmaf(xB2, A2, fabsf(xB2) * B2)))));
        float pC = fmaf(xC0, A0, fmaf(fabsf(xC0), B0, fmaf(xC1, A1, fmaf(fabsf(xC1), B1,
                   fmaf(xC2, A2, fabsf(xC2) * B2)))));
        float pD = fmaf(xD0, A0, fmaf(fabsf(xD0), B0, fmaf(xD1, A1, fmaf(fabsf(xD1), B1,
                   fmaf(xD2, A2, fabsf(xD2) * B2)))));
        pA = sum16(pA); pB = sum16(pB); pC = sum16(pC); pD = sum16(pD);
        float eA = __builtin_amdgcn_exp2f(pA), eB = __builtin_amdgcn_exp2f(pB);
        float eC = __builtin_amdgcn_exp2f(pC), eD = __builtin_amdgcn_exp2f(pD);
        l += (eA + eB) + (eC + eD);
        O0 = fmaf(eA, fA0, O0); O0 = fmaf(eB, fB0, O0);
        O0 = fmaf(eC, fC0, O0); O0 = fmaf(eD, fD0, O0);
        O1 = fmaf(eA, fA1, O1); O1 = fmaf(eB, fB1, O1);
        O1 = fmaf(eC, fC1, O1); O1 = fmaf(eD, fD1, O1);
        O2 = fmaf(eA, fA2, O2); O2 = fmaf(eB, fB2, O2);
        O2 = fmaf(eC, fC2, O2); O2 = fmaf(eD, fD2, O2);
    }
    for (; e < e1; ++e) {
        unsigned b = srcW[e];
        unsigned q = *(const unsigned*)(fsb + b + cbA);
        unsigned short u = *(const unsigned short*)(fsb + b + cbB);
        float f0 = b2flo(q), f1 = b2fhi(q), f2 = b2f(u);
        float x0 = f0 + fd0, x1 = f1 + fd1, x2 = f2 + fd2;
        float p = fmaf(x0, A0, fmaf(fabsf(x0), B0, fmaf(x1, A1, fmaf(fabsf(x1), B1,
                  fmaf(x2, A2, fabsf(x2) * B2)))));
        p = sum16(p);
        float pe = __builtin_amdgcn_exp2f(p);
        l += pe;
        O0 = fmaf(pe, f0, O0);
        O1 = fmaf(pe, f1, O1);
        O2 = fmaf(pe, f2, O2);
    }
    // epilogue: +res, head-mean across lane groups, log_softmax, store
    float inv = l > 0.f ? 1.f / l : 0.f;
    const char* rb_ = (const char*)rs;
    unsigned rqa = *(const unsigned*)(rb_ + drow + cbA);
    unsigned short rqb = *(const unsigned short*)(rb_ + drow + cbB);
    float v0 = fmaf(O0, inv, b2flo(rqa));
    float v1 = fmaf(O1, inv, b2fhi(rqa));
    float v2 = has2 ? fmaf(O2, inv, b2f(rqb)) : 0.f;
    v0 += __shfl_xor(v0, 16); v0 += __shfl_xor(v0, 32); v0 *= 0.25f;
    v1 += __shfl_xor(v1, 16); v1 += __shfl_xor(v1, 32); v1 *= 0.25f;
    v2 += __shfl_xor(v2, 16); v2 += __shfl_xor(v2, 32); v2 *= 0.25f;
    float mx = fmaxf(v0, v1);
    if (has2) mx = fmaxf(mx, v2);
    mx = max16(mx);
    float sm = __expf(v0 - mx) + __expf(v1 - mx) + (has2 ? __expf(v2 - mx) : 0.f);
    sm = sum16(sm);
    if (h == 0) {
        float ls = mx + __log2f(sm) * LN2;
        if (*flag) {
            bf16* o = (bf16*)out + (size_t)d * Cc;
            o[j] = __float2bfloat16(v0 - ls);
            o[j + 16] = __float2bfloat16(v1 - ls);
            if (has2) o[j + 32] = __float2bfloat16(v2 - ls);
        } else {
            float* o = (float*)out + (size_t)d * Cc;
            o[j] = v0 - ls;
            o[j + 16] = v1 - ls;
            if (has2) o[j + 32] = v2 - ls;
        }
    }
}

// ---------------- per-column BN stats over bf16 h (atomic combine) ----------------
// 391 blocks x 128 threads (TWO waves -> latency hiding on the 25.6MB stream;
// the 64-thread ushort2 variant measured slower). ONE atomicAdd per thread per
// stat. (Single-block serial finalize regressed to 92us - never revisit.)
__global__ void col_stats(const bf16* __restrict__ in, float* __restrict__ sums) {
    int c = threadIdx.x;  // 128
    int r0 = blockIdx.x * 256;
    int r1 = r0 + 256; if (r1 > Nn) r1 = Nn;
    float s = 0.f, s2 = 0.f;
    for (int r = r0; r < r1; ++r) {
        float v = ldb(&in[(size_t)r * HD + c]);
        s += v; s2 = fmaf(v, v, s2);
    }
    atomicAdd(&sums[c], s);
    atomicAdd(&sums[HD + c], s2);
}

extern "C" void kernel_launch(void* const* d_in, const int* in_sizes, int n_in,
                              void* d_out, int out_size, void* d_ws, size_t ws_size,
                              hipStream_t stream) {
    (void)in_sizes; (void)n_in; (void)out_size; (void)ws_size;
    const void* x = d_in[0];
    const int* src = (const int*)d_in[1];
    const int* dst = (const int*)d_in[2];

    char* ws = (char*)d_ws;
    size_t off = 0;
    auto alloc = [&](size_t bytes) {
        void* p = ws + off;
        off += (bytes + 255) & ~(size_t)255;
        return p;
    };
    // rs (38.4 MB, [Nn][192]) aliases xb+rb (51.2 MB): both dead before L2 GEMM.
    bf16* xb = (bf16*)alloc((size_t)Nn * 128 * 2);    // 25.6 MB (stride-128 padded x)
    bf16* rb = (bf16*)alloc((size_t)Nn * HD * 2);     // 25.6 MB
    bf16* rs = xb;                                    // [Nn][HCP] alias
    bf16* fs = (bf16*)alloc((size_t)Nn * HCP * 2);    // 38.4 MB
    bf16* fd = (bf16*)alloc((size_t)Nn * HCP * 2);    // 38.4 MB
    bf16* hbA = (bf16*)alloc((size_t)Nn * HD * 2);    // 25.6 MB
    bf16* hbB = (bf16*)alloc((size_t)Nn * HD * 2);    // 25.6 MB
    int* ptr = (int*)alloc((Nn + 1) * 4);             // 400 KB
    bf16* wtb = (bf16*)alloc((size_t)WROWS * 128 * 2);// 328 KB
    float* bns0 = (float*)alloc(2 * HD * 4);
    float* bns1 = (float*)alloc(2 * HD * 4);
    bf16* pb = (bf16*)alloc(4096 * 2);
    int* flag = (int*)alloc(256);
    unsigned* w384 = (unsigned*)alloc((size_t)Ee * 4);// 4 MB
    unsigned* w256 = (unsigned*)alloc((size_t)Ee * 4);// 4 MB
    int* cnt = (int*)alloc((size_t)256 * NBLK * 4);   // 400 KB
    int* cbase = (int*)alloc((size_t)256 * NBLK * 4); // 400 KB
    int* totals = (int*)alloc(256 * 4);
    int* perm = (int*)alloc((size_t)Nn * 4);          // 400 KB

    // ---- small-param conversion (biases/attn/bn): d_in idx -> pb arena ----
    static const int spIdx[NSP] = {4, 6, 7, 9, 11, 13, 14, 16, 18, 19, 21, 22, 23, 24, 25};
    static const int spSz[NSP]  = {HD, HD, HD, HD, HD, HD, HD, HC, HC, HC, HC, HD, HD, HD, HD};
    CvtTab tab;
    int tot = 0;
    for (int i = 0; i < NSP; ++i) { tab.src[i] = d_in[spIdx[i]]; tab.off[i] = tot; tot += spSz[i]; }
    tab.off[NSP] = tot;
    const bf16 *bsrc0 = pb + tab.off[0], *bdst0 = pb + tab.off[1], *attn0 = pb + tab.off[2],
               *bres0 = pb + tab.off[3], *bsrc1 = pb + tab.off[4], *bdst1 = pb + tab.off[5],
               *attn1 = pb + tab.off[6], *bsrc2 = pb + tab.off[7], *bdst2 = pb + tab.off[8],
               *attn2 = pb + tab.off[9], *bres2 = pb + tab.off[10],
               *g0 = pb + tab.off[11], *be0 = pb + tab.off[12],
               *g1 = pb + tab.off[13], *be1 = pb + tab.off[14];

    // ---- packed Wt: rows [0,384)=L0, [384,640)=L1, [640,1216)=L2 @MP=192, pad->1280 ----
    PrepTab pt;
    static const int wIdx[8] = {3, 5, 8, 10, 12, 15, 17, 20};
    static const int wK[8]   = {INF_, INF_, INF_, HD, HD, HD, HD, HD};
    static const int wM[8]   = {HD, HD, HD, HD, HD, HC, HC, HC};
    static const int wMP[8]  = {128, 128, 128, 128, 128, 192, 192, 192};
    static const int wR0[8]  = {0, 128, 256, 384, 512, 640, 832, 1024};
    for (int i = 0; i < 8; ++i) {
        pt.src[i] = d_in[wIdx[i]]; pt.row0[i] = wR0[i];
        pt.K[i] = wK[i]; pt.M[i] = wM[i]; pt.MP[i] = wMP[i];
    }

    // ---- mega prepare (detect + cvt_x + weights + params + src offsets + ptr/hist) --
    const int prepGrid = (Nn * 128 + 255) / 256;   // 50000 blocks, covers all jobs
    prepare<<<prepGrid, 256, 0, stream>>>(x, src, dst, pt, tab, tot,
                                          xb, wtb, pb, w384, w256, ptr, cnt,
                                          bns0, bns1, flag);
    deg_totals<<<64, 256, 0, stream>>>(cnt, totals);
    deg_bases<<<64, 256, 0, stream>>>(cnt, totals, cbase);
    deg_scatter_blk<<<NBLK, 256, 0, stream>>>(ptr, cbase, perm);

    const int fusedGrid = (Nn + 3) / 4;   // 256-thread blocks, 4 dsts each
    const int statsGrid = NBLK;
    const int rowBlk = (Nn + 63) / 64;  // 1563

    // ---------------- layer 0 (384 cols: y=2 x CS=3) ----------------
    gemm_big<128, 3, 3, false, false, HD><<<dim3(rowBlk, 2), 256, 0, stream>>>(
        xb, wtb, bsrc0, bdst0, bres0, fs, fd, rb, HD, nullptr, nullptr, nullptr);
    gat_fused_128<false><<<fusedGrid, 256, 0, stream>>>(fs, fd, w256, ptr, perm,
                                                        attn0, rb, nullptr, nullptr,
                                                        nullptr, hbA);
    col_stats<<<statsGrid, 128, 0, stream>>>(hbA, bns0);

    // ---------------- layer 1 (256 cols: y=2 x CS=2) ----------------
    gemm_big<128, 2, 2, true, false, HD><<<dim3(rowBlk, 2), 256, 0, stream>>>(
        hbA, wtb + (size_t)384 * 128, bsrc1, bdst1, nullptr, fs, fd, nullptr, HD,
        bns0, g0, be0);
    gat_fused_128<true><<<fusedGrid, 256, 0, stream>>>(fs, fd, w256, ptr, perm,
                                                       attn1, hbA, bns0, g0, be0, hbB);
    col_stats<<<statsGrid, 128, 0, stream>>>(hbB, bns1);

    // ---------------- layer 2 (576 cols: y=3 x CS=3, split-pack coalesced outputs) --
    gemm_big<192, 3, 3, true, true, HCP><<<dim3(rowBlk, 3), 256, 0, stream>>>(
        hbB, wtb + (size_t)640 * 128, bsrc2, bdst2, bres2, fs, fd, rs, HC,
        bns1, g1, be1);
    gat_fused_188<<<fusedGrid, 256, 0, stream>>>(fs, fd, w384, ptr, perm, attn2, rs,
                                                 d_out, flag);
}